// Round 13
// baseline (315.275 us; speedup 1.0000x reference)
//
#include <hip/hip_runtime.h>
#include <stdint.h>

#define NB 32      // batch
#define NC 32      // in channels
#define NN 1024    // nodes
#define NT 12      // time
#define NJ (NB*NC*NT)  // 12288
#define NO 32      // out channels
#define TIN 224    // (2*3+1)*32
#define HBE ((size_t)NJ*NN)   // elements per [j][n] buffer

typedef __attribute__((ext_vector_type(8))) __bf16 bf16x8;
typedef __attribute__((ext_vector_type(4))) float f32x4;
typedef unsigned short u16;
typedef unsigned int u32;

__device__ __forceinline__ u16 f2bf(float f){
  u32 u = __float_as_uint(f);
  u32 r = (u + 0x7FFFu + ((u >> 16) & 1u)) >> 16;   // RNE
  return (u16)r;
}
__device__ __forceinline__ float bf2f(u16 h){
  return __uint_as_float(((u32)h) << 16);
}
__device__ __forceinline__ float bflo(u32 v){ return __uint_as_float(v << 16); }
__device__ __forceinline__ float bfhi(u32 v){ return __uint_as_float(v & 0xFFFF0000u); }

typedef const __attribute__((address_space(1))) u32* gp_t;
typedef __attribute__((address_space(3))) u32* lp_t;
__device__ __forceinline__ void gll16(const void* g, void* l){
  __builtin_amdgcn_global_load_lds((gp_t)g, (lp_t)l, 16, 0, 0);
}

// ---------- prep adj: At[z][m][n] = bf16(adj_z[n][m]) ; Ar[z][n][m] = bf16(adj_z[n][m]) ----------
__global__ __launch_bounds__(256) void k_prep_adj(const float* __restrict__ a0,
      const float* __restrict__ a1, const float* __restrict__ a2,
      u16* __restrict__ At, u16* __restrict__ Ar){
  __shared__ float tile[32][33];
  const float* A = (blockIdx.z==0) ? a0 : (blockIdx.z==1 ? a1 : a2);
  int n0 = blockIdx.x*32, m0 = blockIdx.y*32;
  int tx = threadIdx.x, ty = threadIdx.y;  // block (32,8)
  u16* dstR = Ar + (size_t)blockIdx.z*NN*NN;
  #pragma unroll
  for (int r=0;r<4;r++){
    float v = A[(size_t)(n0 + ty + 8*r)*NN + m0 + tx];
    tile[ty + 8*r][tx] = v;
    dstR[(size_t)(n0 + ty + 8*r)*NN + m0 + tx] = f2bf(v);
  }
  __syncthreads();
  u16* dst = At + (size_t)blockIdx.z*NN*NN;
  #pragma unroll
  for (int r=0;r<4;r++)
    dst[(size_t)(m0 + ty + 8*r)*NN + n0 + tx] = f2bf(tile[tx][ty + 8*r]);
}

// ---------- prep x (fallback layout): Zt[j][n] = bf16(x[p,n,t]) ----------
__global__ __launch_bounds__(256) void k_prep_x2(const float* __restrict__ x, u16* __restrict__ Zt){
  __shared__ float tl[64][13];
  int p = blockIdx.y, n0 = blockIdx.x*64;
  const float* xp = x + (size_t)p*NN*NT + (size_t)n0*NT;
  int tid = threadIdx.x;
  #pragma unroll
  for (int k=0;k<3;k++){
    int e = tid + k*256;
    float v = xp[e];
    tl[e/12][e%12] = v;
  }
  __syncthreads();
  #pragma unroll
  for (int k=0;k<3;k++){
    int e = tid + k*256;
    int t = e >> 6, nn = e & 63;
    Zt[((size_t)p*NT + t)*NN + n0 + nn] = f2bf(tl[nn][t]);
  }
}

// ---------- prep x (primary): Zc[(b*12+t)][n][c] = bf16(x[b,c,n,t]) ----------
__global__ __launch_bounds__(256) void k_prep_x3(const float* __restrict__ x,
                                                 u16* __restrict__ Zc){
  __shared__ u16 T[32*780];   // [c][n 64][t 12] u16, 49.9 KB
  int tid = threadIdx.x;
  int n0 = blockIdx.x*64, b = blockIdx.y;
  #pragma unroll
  for (int k=0;k<24;k++){
    int idx = tid + k*256;            // 6144 float4 per block
    int c = idx / 192, f = idx - c*192;
    float4 v = *reinterpret_cast<const float4*>(
        x + ((size_t)(b*NC + c)*NN + n0)*NT + f*4);
    #pragma unroll
    for (int j=0;j<4;j++){
      int e = f*4 + j;
      int nl = e / 12, tt = e - nl*12;
      float fv = (j==0)?v.x:(j==1)?v.y:(j==2)?v.z:v.w;
      T[c*780 + nl*12 + tt] = f2bf(fv);
    }
  }
  __syncthreads();
  #pragma unroll
  for (int k=0;k<48;k++){
    int i = tid + k*256;              // 12288 u32 per block
    int tt = i >> 10, rem = i & 1023, nl = rem >> 4, cp = rem & 15;
    u32 lo = T[(2*cp)*780 + nl*12 + tt];
    u32 hi = T[(2*cp+1)*780 + nl*12 + tt];
    *reinterpret_cast<u32*>(Zc + (((size_t)(b*NT + tt)*NN + n0 + nl) << 5) + 2*cp)
        = lo | (hi << 16);
  }
}

// ---------- MFMA premix (R11-proven) ----------
__global__ __launch_bounds__(256) void k_pmix(const u16* __restrict__ Zc,
    const float* __restrict__ W, const float* __restrict__ bias,
    u16* __restrict__ U, u16* __restrict__ Base){
  __shared__ __align__(16) u16 Xl[16384];   // 512 n x 32 c, 32 KB
  int tid = threadIdx.x;
  int w = tid >> 6, lane = tid & 63;
  int lrow = lane & 15, kgrp = lane >> 4;
  int nh = blockIdx.x;               // n-half (512)
  int bt = blockIdx.y;               // b*12 + t
  int b = bt / NT, t = bt - b*NT;

  const u16* src = Zc + ((size_t)bt*NN + (size_t)nh*512)*32;
  #pragma unroll
  for (int k=0;k<8;k++){
    int chunk = w*8 + k;
    gll16(src + (size_t)chunk*512 + lane*8, (u16*)Xl + chunk*512);
  }

  bf16x8 af[7][2];
  #pragma unroll
  for (int g=0; g<7; g++){
    #pragma unroll
    for (int ot=0; ot<2; ot++){
      const float* wr = W + (size_t)(ot*16 + lrow)*TIN + g*32 + kgrp*8;
      float4 wa = *reinterpret_cast<const float4*>(wr);
      float4 wb = *reinterpret_cast<const float4*>(wr + 4);
      u32 tmp[4];
      tmp[0] = (u32)f2bf(wa.x) | ((u32)f2bf(wa.y) << 16);
      tmp[1] = (u32)f2bf(wa.z) | ((u32)f2bf(wa.w) << 16);
      tmp[2] = (u32)f2bf(wb.x) | ((u32)f2bf(wb.y) << 16);
      tmp[3] = (u32)f2bf(wb.z) | ((u32)f2bf(wb.w) << 16);
      af[g][ot] = *reinterpret_cast<bf16x8*>(tmp);
    }
  }
  float4 bias4[2];
  #pragma unroll
  for (int ot=0; ot<2; ot++)
    bias4[ot] = *reinterpret_cast<const float4*>(bias + ot*16 + kgrp*4);

  __syncthreads();

  #pragma unroll
  for (int nt=0; nt<8; nt++){
    int row = w*128 + nt*16 + lrow;
    int n = nh*512 + row;
    bf16x8 bfr = *reinterpret_cast<const bf16x8*>(&Xl[row*32 + kgrp*8]);
    #pragma unroll
    for (int g=0; g<7; g++){
      u16* dstb = (g==0) ? Base : (U + (size_t)(g-1)*HBE);
      #pragma unroll
      for (int ot=0; ot<2; ot++){
        f32x4 acc = (f32x4){0.f,0.f,0.f,0.f};
        acc = __builtin_amdgcn_mfma_f32_16x16x32_bf16(af[g][ot], bfr, acc, 0, 0, 0);
        if (g==0){
          acc[0] += bias4[ot].x; acc[1] += bias4[ot].y;
          acc[2] += bias4[ot].z; acc[3] += bias4[ot].w;
        }
        int o = ot*16 + kgrp*4;
        size_t rb = ((size_t)(b*NO + o)*NT + t)*NN + n;
        dstb[rb]                    = f2bf(acc[0]);
        dstb[rb + (size_t)NT*NN]    = f2bf(acc[1]);
        dstb[rb + (size_t)2*NT*NN]  = f2bf(acc[2]);
        dstb[rb + (size_t)3*NT*NN]  = f2bf(acc[3]);
      }
    }
  }
}

// ---------- batched GEMM, 2-phase double-buffered (fallback + At2), MODE0/2/3 ----------
#define BKK 64
template<int MODE>
__global__ __launch_bounds__(256) void k_bgemm(
    const u16* __restrict__ At, const u16* __restrict__ Ar,
    u16* __restrict__ At2, const u16* __restrict__ Zt,
    u16* __restrict__ Db){
  __shared__ __align__(16) u16 As[2][128*BKK];
  __shared__ __align__(16) u16 Bs[2][128*BKK];
  int tid = threadIdx.x;
  int w = tid >> 6, lane = tid & 63;
  int z = blockIdx.z;
  int m0 = blockIdx.y * 128, j0 = blockIdx.x * 128;
  int wr = w >> 1, wc = w & 1;
  int lrow = lane & 15, kgrp = lane >> 4;
  int lr8 = lane >> 3, lc8 = lane & 7;

  const u16* Amat; const u16* Bmat; u16* Out;
  if (MODE==0){
    Amat = Ar + (size_t)z*NN*NN; Bmat = At + (size_t)z*NN*NN; Out = At2 + (size_t)z*NN*NN;
  } else if (MODE==2){
    Amat = At + (size_t)z*NN*NN; Bmat = Zt; Out = Db + (size_t)(2*z)*HBE;
  } else {
    Amat = At + (size_t)z*NN*NN; Bmat = Db + (size_t)(2*z)*HBE; Out = Db + (size_t)(2*z+1)*HBE;
  }

  f32x4 acc[4][4];
  #pragma unroll
  for (int i=0;i<4;i++)
    #pragma unroll
    for (int jj=0;jj<4;jj++)
      acc[i][jj] = (f32x4){0.f,0.f,0.f,0.f};

  const u16* Abase = Amat + (size_t)m0*1024;
  const u16* Bbase = Bmat + (size_t)j0*1024;

  auto stage = [&](int kt, int d){
    int k0 = kt*BKK;
    #pragma unroll
    for (int i=0;i<4;i++){
      int q = w*4 + i;
      int row = q*8 + lr8;
      gll16(Abase + (size_t)row*1024 + k0 + lc8*8, (u16*)&As[d][0] + q*512);
      gll16(Bbase + (size_t)row*1024 + k0 + lc8*8, (u16*)&Bs[d][0] + q*512);
    }
  };
  auto compute = [&](int d){
    #pragma unroll
    for (int kk=0; kk<2; ++kk){
      bf16x8 af[4], bfr[4];
      #pragma unroll
      for (int mi=0;mi<4;mi++)
        af[mi] = *reinterpret_cast<const bf16x8*>(&As[d][(wr*64+mi*16+lrow)*BKK + kk*32 + kgrp*8]);
      #pragma unroll
      for (int ji=0;ji<4;ji++)
        bfr[ji] = *reinterpret_cast<const bf16x8*>(&Bs[d][(wc*64+ji*16+lrow)*BKK + kk*32 + kgrp*8]);
      #pragma unroll
      for (int mi=0;mi<4;mi++)
        #pragma unroll
        for (int ji=0;ji<4;ji++)
          acc[mi][ji] = __builtin_amdgcn_mfma_f32_16x16x32_bf16(af[mi], bfr[ji], acc[mi][ji], 0, 0, 0);
    }
  };

  stage(0, 0);
  #pragma unroll 1
  for (int kt2=0; kt2<8; ++kt2){
    stage(2*kt2+1, 1);
    asm volatile("s_waitcnt vmcnt(8)" ::: "memory");
    __builtin_amdgcn_s_barrier();
    compute(0);
    __builtin_amdgcn_s_barrier();
    if (kt2 < 7){
      stage(2*kt2+2, 0);
      asm volatile("s_waitcnt vmcnt(8)" ::: "memory");
    } else {
      asm volatile("s_waitcnt vmcnt(0)" ::: "memory");
    }
    __builtin_amdgcn_s_barrier();
    compute(1);
    __builtin_amdgcn_s_barrier();
  }

  #pragma unroll
  for (int mi=0;mi<4;mi++){
    #pragma unroll
    for (int ji=0;ji<4;ji++){
      int jg = j0 + wc*64 + ji*16 + lrow;
      int mg = m0 + wr*64 + mi*16 + kgrp*4;
      ushort4 st;
      st.x = f2bf(acc[mi][ji][0]);
      st.y = f2bf(acc[mi][ji][1]);
      st.z = f2bf(acc[mi][ji][2]);
      st.w = f2bf(acc[mi][ji][3]);
      *reinterpret_cast<ushort4*>(&Out[(size_t)jg*NN + mg]) = st;
    }
  }
}

// ---------- fused 6-term GEMM v3: 128x192 tile, 4 waves, 80KB LDS -> 2 blocks/CU ----------
// Same R11-proven schedule (stage-spread + counted vmcnt + swizzle + setprio);
// the 2 waves on each SIMD belong to DIFFERENT blocks (independent barriers) ->
// one block's MFMA covers the other's barrier/ds_read stalls. Each XCD owns one
// 128-row A-panel (1.5 MB, L2-resident); U (151 MB) is L3-resident for B re-reads.
__global__ __launch_bounds__(256) void k_gemm6p(
    const u16* __restrict__ At, const u16* __restrict__ At2,
    const u16* __restrict__ U, const u16* __restrict__ Base,
    u16* __restrict__ Y){
  __shared__ __align__(16) u16 lds[2][20480];   // per buf: A 128x64 @0, B 192x64 @8192 (40 KB)
  const int tid = threadIdx.x;
  const int w = tid >> 6, lane = tid & 63;
  const int lrow = lane & 15, kgrp = lane >> 4;
  const int wm = w & 1, wj = w >> 1;
  const int swz = (lrow & 7) << 3;           // read-side XOR (u16 units, 16B slots)

  const int orig = blockIdx.x;
  const int wg = (orig & 7)*64 + (orig >> 3);  // bijective XCD remap (512 = 8*64)
  const int m0 = (wg >> 6) * 128;              // m-tile 0..7 == XCD id
  const int j0 = (wg & 63) * 192;

  const int srow = lane >> 3;
  const int skoff = ((lane & 7) << 3) ^ ((srow & 7) << 3);   // inverse-swizzled k-off

  // 40 chunks of 1KB (A:0..15, B:16..39), 10 per wave
  size_t rowoff[10]; int ldsoff[10]; bool isA[10];
  #pragma unroll
  for (int i=0;i<10;i++){
    int c = w*10 + i;
    if (c < 16){
      isA[i] = true;
      rowoff[i] = (size_t)(m0 + c*8 + srow)*1024 + skoff;
      ldsoff[i] = c*512;
    } else {
      int cb = c - 16;
      isA[i] = false;
      rowoff[i] = (size_t)(j0 + cb*8 + srow)*1024 + skoff;
      ldsoff[i] = 8192 + cb*512;
    }
  }

  #define STAGE(t, i) {                                                        \
    int s_ = (t) >> 4;                                                         \
    int k0_ = ((t) & 15) << 6;                                                 \
    const u16* Ab_ = ((s_ & 1) ? At2 : At) + (size_t)(s_ >> 1)*NN*NN;          \
    const u16* src_ = (isA[i] ? Ab_ : (U + (size_t)s_*HBE)) + rowoff[i] + k0_; \
    gll16(src_, &lds[(t) & 1][ldsoff[i]]); }

  f32x4 acc[4][6];
  #pragma unroll
  for (int mi=0;mi<4;mi++)
    #pragma unroll
    for (int ji=0;ji<6;ji++)
      acc[mi][ji] = (f32x4){0.f,0.f,0.f,0.f};

  // prologue: fully stage tile 0
  #pragma unroll
  for (int i=0;i<10;i++) STAGE(0, i)

  #pragma unroll 1
  for (int t=0; t<96; ++t){
    const int d = t & 1;
    if (t < 95){
      STAGE(t+1, 0) STAGE(t+1, 1) STAGE(t+1, 2)
      asm volatile("s_waitcnt vmcnt(3)" ::: "memory");   // tile t's 10 retired
    } else {
      asm volatile("s_waitcnt vmcnt(0)" ::: "memory");
    }
    __builtin_amdgcn_s_barrier();
    __builtin_amdgcn_sched_barrier(0);

    bf16x8 bf[6][2];
    #pragma unroll
    for (int p=0;p<4;p++){
      if (t < 95){
        if (p==0){ STAGE(t+1, 3) STAGE(t+1, 4) STAGE(t+1, 5) }
        else if (p==1){ STAGE(t+1, 6) STAGE(t+1, 7) }
        else if (p==2){ STAGE(t+1, 8) STAGE(t+1, 9) }
      }
      if (p==0){
        #pragma unroll
        for (int ji=0;ji<6;ji++){
          int row = wj*96 + ji*16 + lrow;
          #pragma unroll
          for (int kk=0;kk<2;kk++)
            bf[ji][kk] = *reinterpret_cast<const bf16x8*>(
              &lds[d][8192 + row*64 + ((kk*32 + kgrp*8) ^ swz)]);
        }
      }
      bf16x8 af0, af1;
      {
        int row = wm*64 + p*16 + lrow;
        af0 = *reinterpret_cast<const bf16x8*>(&lds[d][row*64 + ((kgrp*8) ^ swz)]);
        af1 = *reinterpret_cast<const bf16x8*>(&lds[d][row*64 + ((32 + kgrp*8) ^ swz)]);
      }
      __builtin_amdgcn_s_setprio(1);
      #pragma unroll
      for (int ji=0;ji<6;ji++){
        acc[p][ji] = __builtin_amdgcn_mfma_f32_16x16x32_bf16(af0, bf[ji][0], acc[p][ji], 0, 0, 0);
        acc[p][ji] = __builtin_amdgcn_mfma_f32_16x16x32_bf16(af1, bf[ji][1], acc[p][ji], 0, 0, 0);
      }
      __builtin_amdgcn_s_setprio(0);
    }
    __builtin_amdgcn_s_barrier();   // all waves done reading buf d before t+2 stages hit it
  }
  #undef STAGE

  #pragma unroll
  for (int mi=0;mi<4;mi++){
    #pragma unroll
    for (int ji=0;ji<6;ji++){
      int jg = j0 + wj*96 + ji*16 + lrow;
      int mg = m0 + wm*64 + mi*16 + kgrp*4;
      const ushort4 bv = *reinterpret_cast<const ushort4*>(&Base[(size_t)jg*NN + mg]);
      ushort4 st;
      st.x = f2bf(acc[mi][ji][0] + bf2f(bv.x));
      st.y = f2bf(acc[mi][ji][1] + bf2f(bv.y));
      st.z = f2bf(acc[mi][ji][2] + bf2f(bv.z));
      st.w = f2bf(acc[mi][ji][3] + bf2f(bv.w));
      *reinterpret_cast<ushort4*>(&Y[(size_t)jg*NN + mg]) = st;
    }
  }
}

// ---------- final channel mix (fallback path only) ----------
__global__ __launch_bounds__(256) void k_mix7(u16* zt_y,
    const u16* __restrict__ Db, const float* __restrict__ W,
    const float* __restrict__ bias){
  __shared__ u32 X[112][64];   // 28 KB
  int tid = threadIdx.x;
  int n0 = blockIdx.x*128;
  int bt = blockIdx.y;
  int b = bt / NT, t = bt - b*NT;
  int lane = tid & 63;
  int og = __builtin_amdgcn_readfirstlane(tid >> 6);

  float a0[8], a1[8];
  #pragma unroll
  for (int oo=0;oo<8;oo++){ float bv = bias[og*8+oo]; a0[oo]=bv; a1[oo]=bv; }

  #pragma unroll 1
  for (int chunk=0; chunk<2; ++chunk){
    if (chunk) __syncthreads();
    #pragma unroll
    for (int k=0;k<28;k++){
      int i = tid + k*256;
      int rl = i >> 6, col = i & 63;
      int r = chunk*112 + rl;
      int s = r >> 5, c = r & 31;
      const u16* src = (s==0) ? zt_y : (Db + (size_t)(s-1)*HBE);
      X[rl][col] = *reinterpret_cast<const u32*>(src + ((size_t)(b*NC + c)*NT + t)*NN + n0 + 2*col);
    }
    __syncthreads();
    #pragma unroll
    for (int cc=0; cc<112; ++cc){
      u32 xp = X[cc][lane];
      float xl = bflo(xp), xh = bfhi(xp);
      #pragma unroll
      for (int oo=0;oo<8;oo++){
        float w = W[(size_t)(og*8+oo)*TIN + chunk*112 + cc];
        a0[oo] += w*xl; a1[oo] += w*xh;
      }
    }
  }

  #pragma unroll
  for (int oo=0;oo<8;oo++){
    u32 pk = (u32)f2bf(a0[oo]) | ((u32)f2bf(a1[oo]) << 16);
    *reinterpret_cast<u32*>(zt_y + ((size_t)(b*NO + og*8+oo)*NT + t)*NN + n0 + 2*lane) = pk;
  }
}

// ---------- final transpose v2 (vectorized): y[b,o,n,t] = f32(Yb[(b*32+o)*12+t][n]) ----------
__global__ __launch_bounds__(256) void k_out3(const u16* __restrict__ Yb,
                                              float* __restrict__ y){
  __shared__ float tl[512][13];   // 26.6 KB
  int n0 = blockIdx.x*512;
  int bo = blockIdx.y;               // b*32 + o
  int tid = threadIdx.x;
  #pragma unroll
  for (int k=0;k<12;k++){
    u32 v = *reinterpret_cast<const u32*>(Yb + ((size_t)bo*NT + k)*NN + n0 + 2*tid);
    tl[2*tid][k]   = bflo(v);
    tl[2*tid+1][k] = bfhi(v);
  }
  __syncthreads();
  float* yp = y + ((size_t)bo*NN + n0)*NT;   // 6144 consecutive floats
  #pragma unroll
  for (int q=0;q<6;q++){
    int idx = tid + q*256;
    int e = idx*4;
    float4 v;
    v.x = tl[(e+0)/12][(e+0)%12];
    v.y = tl[(e+1)/12][(e+1)%12];
    v.z = tl[(e+2)/12][(e+2)%12];
    v.w = tl[(e+3)/12][(e+3)%12];
    *reinterpret_cast<float4*>(yp + e) = v;
  }
}

// ---------- final transpose (fallback path) ----------
__global__ __launch_bounds__(256) void k_out2(const u16* __restrict__ Yb,
                                              float* __restrict__ y){
  __shared__ float tl[256][13];
  int n0 = blockIdx.x*256;
  int bo = blockIdx.y;
  int tid = threadIdx.x;
  #pragma unroll
  for (int k=0;k<12;k++)
    tl[tid][k] = bf2f(Yb[((size_t)bo*NT + k)*NN + n0 + tid]);
  __syncthreads();
  float* yp = y + ((size_t)bo*NN + n0)*NT;
  #pragma unroll
  for (int k=0;k<12;k++){
    int i = k*256 + tid;
    yp[i] = tl[i/12][i%12];
  }
}

extern "C" void kernel_launch(void* const* d_in, const int* in_sizes, int n_in,
                              void* d_out, int out_size, void* d_ws, size_t ws_size,
                              hipStream_t stream){
  const float* x    = (const float*)d_in[0];
  const float* a0   = (const float*)d_in[1];
  const float* a1   = (const float*)d_in[2];
  const float* a2   = (const float*)d_in[3];
  const float* W    = (const float*)d_in[4];
  const float* bias = (const float*)d_in[5];
  float* y = (float*)d_out;
  (void)in_sizes; (void)n_in; (void)out_size;

  const size_t atB = (size_t)3*NN*NN*2;     // 6.29 MB
  const size_t ztB = HBE*2;                 // 25.17 MB
  const size_t need_fused = 2*atB + 8*ztB;  // 213.9 MB (R9-R12 verified available)

  if (ws_size >= need_fused){
    char* ws = (char*)d_ws;
    u16* At   = (u16*)ws;  ws += atB;
    u16* At2  = (u16*)ws;  ws += atB;
    u16* Zt   = (u16*)ws;  ws += ztB;       // holds Zc, then Y after k_gemm6p
    u16* U    = (u16*)ws;  ws += 6*ztB;
    u16* Base = (u16*)ws;  ws += ztB;
    u16* Ar   = Base;                        // dead after k_bgemm<0>

    k_prep_adj<<<dim3(32,32,3), dim3(32,8), 0, stream>>>(a0, a1, a2, At, Ar);
    k_bgemm<0><<<dim3(NN/128, NN/128, 3), 256, 0, stream>>>(At, Ar, At2, Zt, U);
    k_prep_x3<<<dim3(NN/64, NB), 256, 0, stream>>>(x, Zt);          // Zc
    k_pmix<<<dim3(2, NB*NT), 256, 0, stream>>>(Zt, W, bias, U, Base);
    k_gemm6p<<<512, 256, 0, stream>>>(At, At2, U, Base, Zt);        // Y over Zc
    k_out3<<<dim3(NN/512, NB*NO), 256, 0, stream>>>(Zt, y);
  } else {
    // fallback: two dependent batched GEMM dispatches + late mix
    char* ws = (char*)d_ws;
    u16* At  = (u16*)ws;  ws += atB;
    u16* Zt  = (u16*)ws;  ws += ztB;
    u16* Db  = (u16*)ws;  ws += 6*ztB;
    u16* Ar  = Db + 6*HBE - (size_t)3*NN*NN;

    k_prep_adj<<<dim3(32,32,3), dim3(32,8), 0, stream>>>(a0, a1, a2, At, Ar);
    k_prep_x2 <<<dim3(NN/64, NB*NC), 256, 0, stream>>>(x, Zt);
    k_bgemm<2><<<dim3(NJ/128, NN/128, 3), 256, 0, stream>>>(At, Ar, At, Zt, Db);
    k_bgemm<3><<<dim3(NJ/128, NN/128, 3), 256, 0, stream>>>(At, Ar, At, Zt, Db);
    k_mix7<<<dim3(NN/128, NB*NT), 256, 0, stream>>>(Zt, Db, W, bias);
    k_out2<<<dim3(NN/256, NB*NO), 256, 0, stream>>>(Zt, y);
  }
}

// Round 14
// 307.106 us; speedup vs baseline: 1.0266x; 1.0266x over previous
//
#include <hip/hip_runtime.h>
#include <stdint.h>

#define NB 32      // batch
#define NC 32      // in channels
#define NN 1024    // nodes
#define NT 12      // time
#define NJ (NB*NC*NT)  // 12288
#define NO 32      // out channels
#define TIN 224    // (2*3+1)*32
#define HBE ((size_t)NJ*NN)   // elements per [j][n] buffer

typedef __attribute__((ext_vector_type(8))) __bf16 bf16x8;
typedef __attribute__((ext_vector_type(4))) float f32x4;
typedef unsigned short u16;
typedef unsigned int u32;

__device__ __forceinline__ u16 f2bf(float f){
  u32 u = __float_as_uint(f);
  u32 r = (u + 0x7FFFu + ((u >> 16) & 1u)) >> 16;   // RNE
  return (u16)r;
}
__device__ __forceinline__ float bf2f(u16 h){
  return __uint_as_float(((u32)h) << 16);
}
__device__ __forceinline__ float bflo(u32 v){ return __uint_as_float(v << 16); }
__device__ __forceinline__ float bfhi(u32 v){ return __uint_as_float(v & 0xFFFF0000u); }

typedef const __attribute__((address_space(1))) u32* gp_t;
typedef __attribute__((address_space(3))) u32* lp_t;
__device__ __forceinline__ void gll16(const void* g, void* l){
  __builtin_amdgcn_global_load_lds((gp_t)g, (lp_t)l, 16, 0, 0);
}

// ---------- prep adj: At[z][m][n] = bf16(adj_z[n][m]) ; Ar[z][n][m] = bf16(adj_z[n][m]) ----------
__global__ __launch_bounds__(256) void k_prep_adj(const float* __restrict__ a0,
      const float* __restrict__ a1, const float* __restrict__ a2,
      u16* __restrict__ At, u16* __restrict__ Ar){
  __shared__ float tile[32][33];
  const float* A = (blockIdx.z==0) ? a0 : (blockIdx.z==1 ? a1 : a2);
  int n0 = blockIdx.x*32, m0 = blockIdx.y*32;
  int tx = threadIdx.x, ty = threadIdx.y;  // block (32,8)
  u16* dstR = Ar + (size_t)blockIdx.z*NN*NN;
  #pragma unroll
  for (int r=0;r<4;r++){
    float v = A[(size_t)(n0 + ty + 8*r)*NN + m0 + tx];
    tile[ty + 8*r][tx] = v;
    dstR[(size_t)(n0 + ty + 8*r)*NN + m0 + tx] = f2bf(v);
  }
  __syncthreads();
  u16* dst = At + (size_t)blockIdx.z*NN*NN;
  #pragma unroll
  for (int r=0;r<4;r++)
    dst[(size_t)(m0 + ty + 8*r)*NN + n0 + tx] = f2bf(tile[tx][ty + 8*r]);
}

// ---------- prep x (fallback layout): Zt[j][n] = bf16(x[p,n,t]) ----------
__global__ __launch_bounds__(256) void k_prep_x2(const float* __restrict__ x, u16* __restrict__ Zt){
  __shared__ float tl[64][13];
  int p = blockIdx.y, n0 = blockIdx.x*64;
  const float* xp = x + (size_t)p*NN*NT + (size_t)n0*NT;
  int tid = threadIdx.x;
  #pragma unroll
  for (int k=0;k<3;k++){
    int e = tid + k*256;
    float v = xp[e];
    tl[e/12][e%12] = v;
  }
  __syncthreads();
  #pragma unroll
  for (int k=0;k<3;k++){
    int e = tid + k*256;
    int t = e >> 6, nn = e & 63;
    Zt[((size_t)p*NT + t)*NN + n0 + nn] = f2bf(tl[nn][t]);
  }
}

// ---------- prep x (primary): Zc[(b*12+t)][n][c] = bf16(x[b,c,n,t]) ----------
__global__ __launch_bounds__(256) void k_prep_x3(const float* __restrict__ x,
                                                 u16* __restrict__ Zc){
  __shared__ u16 T[32*780];   // [c][n 64][t 12] u16, 49.9 KB
  int tid = threadIdx.x;
  int n0 = blockIdx.x*64, b = blockIdx.y;
  #pragma unroll
  for (int k=0;k<24;k++){
    int idx = tid + k*256;            // 6144 float4 per block
    int c = idx / 192, f = idx - c*192;
    float4 v = *reinterpret_cast<const float4*>(
        x + ((size_t)(b*NC + c)*NN + n0)*NT + f*4);
    #pragma unroll
    for (int j=0;j<4;j++){
      int e = f*4 + j;
      int nl = e / 12, tt = e - nl*12;
      float fv = (j==0)?v.x:(j==1)?v.y:(j==2)?v.z:v.w;
      T[c*780 + nl*12 + tt] = f2bf(fv);
    }
  }
  __syncthreads();
  #pragma unroll
  for (int k=0;k<48;k++){
    int i = tid + k*256;              // 12288 u32 per block
    int tt = i >> 10, rem = i & 1023, nl = rem >> 4, cp = rem & 15;
    u32 lo = T[(2*cp)*780 + nl*12 + tt];
    u32 hi = T[(2*cp+1)*780 + nl*12 + tt];
    *reinterpret_cast<u32*>(Zc + (((size_t)(b*NT + tt)*NN + n0 + nl) << 5) + 2*cp)
        = lo | (hi << 16);
  }
}

// ---------- MFMA premix (R11-proven) ----------
__global__ __launch_bounds__(256) void k_pmix(const u16* __restrict__ Zc,
    const float* __restrict__ W, const float* __restrict__ bias,
    u16* __restrict__ U, u16* __restrict__ Base){
  __shared__ __align__(16) u16 Xl[16384];   // 512 n x 32 c, 32 KB
  int tid = threadIdx.x;
  int w = tid >> 6, lane = tid & 63;
  int lrow = lane & 15, kgrp = lane >> 4;
  int nh = blockIdx.x;               // n-half (512)
  int bt = blockIdx.y;               // b*12 + t
  int b = bt / NT, t = bt - b*NT;

  const u16* src = Zc + ((size_t)bt*NN + (size_t)nh*512)*32;
  #pragma unroll
  for (int k=0;k<8;k++){
    int chunk = w*8 + k;
    gll16(src + (size_t)chunk*512 + lane*8, (u16*)Xl + chunk*512);
  }

  bf16x8 af[7][2];
  #pragma unroll
  for (int g=0; g<7; g++){
    #pragma unroll
    for (int ot=0; ot<2; ot++){
      const float* wr = W + (size_t)(ot*16 + lrow)*TIN + g*32 + kgrp*8;
      float4 wa = *reinterpret_cast<const float4*>(wr);
      float4 wb = *reinterpret_cast<const float4*>(wr + 4);
      u32 tmp[4];
      tmp[0] = (u32)f2bf(wa.x) | ((u32)f2bf(wa.y) << 16);
      tmp[1] = (u32)f2bf(wa.z) | ((u32)f2bf(wa.w) << 16);
      tmp[2] = (u32)f2bf(wb.x) | ((u32)f2bf(wb.y) << 16);
      tmp[3] = (u32)f2bf(wb.z) | ((u32)f2bf(wb.w) << 16);
      af[g][ot] = *reinterpret_cast<bf16x8*>(tmp);
    }
  }
  float4 bias4[2];
  #pragma unroll
  for (int ot=0; ot<2; ot++)
    bias4[ot] = *reinterpret_cast<const float4*>(bias + ot*16 + kgrp*4);

  __syncthreads();

  #pragma unroll
  for (int nt=0; nt<8; nt++){
    int row = w*128 + nt*16 + lrow;
    int n = nh*512 + row;
    bf16x8 bfr = *reinterpret_cast<const bf16x8*>(&Xl[row*32 + kgrp*8]);
    #pragma unroll
    for (int g=0; g<7; g++){
      u16* dstb = (g==0) ? Base : (U + (size_t)(g-1)*HBE);
      #pragma unroll
      for (int ot=0; ot<2; ot++){
        f32x4 acc = (f32x4){0.f,0.f,0.f,0.f};
        acc = __builtin_amdgcn_mfma_f32_16x16x32_bf16(af[g][ot], bfr, acc, 0, 0, 0);
        if (g==0){
          acc[0] += bias4[ot].x; acc[1] += bias4[ot].y;
          acc[2] += bias4[ot].z; acc[3] += bias4[ot].w;
        }
        int o = ot*16 + kgrp*4;
        size_t rb = ((size_t)(b*NO + o)*NT + t)*NN + n;
        dstb[rb]                    = f2bf(acc[0]);
        dstb[rb + (size_t)NT*NN]    = f2bf(acc[1]);
        dstb[rb + (size_t)2*NT*NN]  = f2bf(acc[2]);
        dstb[rb + (size_t)3*NT*NN]  = f2bf(acc[3]);
      }
    }
  }
}

// ---------- batched GEMM, 2-phase double-buffered (fallback + At2), MODE0/2/3 ----------
#define BKK 64
template<int MODE>
__global__ __launch_bounds__(256) void k_bgemm(
    const u16* __restrict__ At, const u16* __restrict__ Ar,
    u16* __restrict__ At2, const u16* __restrict__ Zt,
    u16* __restrict__ Db){
  __shared__ __align__(16) u16 As[2][128*BKK];
  __shared__ __align__(16) u16 Bs[2][128*BKK];
  int tid = threadIdx.x;
  int w = tid >> 6, lane = tid & 63;
  int z = blockIdx.z;
  int m0 = blockIdx.y * 128, j0 = blockIdx.x * 128;
  int wr = w >> 1, wc = w & 1;
  int lrow = lane & 15, kgrp = lane >> 4;
  int lr8 = lane >> 3, lc8 = lane & 7;

  const u16* Amat; const u16* Bmat; u16* Out;
  if (MODE==0){
    Amat = Ar + (size_t)z*NN*NN; Bmat = At + (size_t)z*NN*NN; Out = At2 + (size_t)z*NN*NN;
  } else if (MODE==2){
    Amat = At + (size_t)z*NN*NN; Bmat = Zt; Out = Db + (size_t)(2*z)*HBE;
  } else {
    Amat = At + (size_t)z*NN*NN; Bmat = Db + (size_t)(2*z)*HBE; Out = Db + (size_t)(2*z+1)*HBE;
  }

  f32x4 acc[4][4];
  #pragma unroll
  for (int i=0;i<4;i++)
    #pragma unroll
    for (int jj=0;jj<4;jj++)
      acc[i][jj] = (f32x4){0.f,0.f,0.f,0.f};

  const u16* Abase = Amat + (size_t)m0*1024;
  const u16* Bbase = Bmat + (size_t)j0*1024;

  auto stage = [&](int kt, int d){
    int k0 = kt*BKK;
    #pragma unroll
    for (int i=0;i<4;i++){
      int q = w*4 + i;
      int row = q*8 + lr8;
      gll16(Abase + (size_t)row*1024 + k0 + lc8*8, (u16*)&As[d][0] + q*512);
      gll16(Bbase + (size_t)row*1024 + k0 + lc8*8, (u16*)&Bs[d][0] + q*512);
    }
  };
  auto compute = [&](int d){
    #pragma unroll
    for (int kk=0; kk<2; ++kk){
      bf16x8 af[4], bfr[4];
      #pragma unroll
      for (int mi=0;mi<4;mi++)
        af[mi] = *reinterpret_cast<const bf16x8*>(&As[d][(wr*64+mi*16+lrow)*BKK + kk*32 + kgrp*8]);
      #pragma unroll
      for (int ji=0;ji<4;ji++)
        bfr[ji] = *reinterpret_cast<const bf16x8*>(&Bs[d][(wc*64+ji*16+lrow)*BKK + kk*32 + kgrp*8]);
      #pragma unroll
      for (int mi=0;mi<4;mi++)
        #pragma unroll
        for (int ji=0;ji<4;ji++)
          acc[mi][ji] = __builtin_amdgcn_mfma_f32_16x16x32_bf16(af[mi], bfr[ji], acc[mi][ji], 0, 0, 0);
    }
  };

  stage(0, 0);
  #pragma unroll 1
  for (int kt2=0; kt2<8; ++kt2){
    stage(2*kt2+1, 1);
    asm volatile("s_waitcnt vmcnt(8)" ::: "memory");
    __builtin_amdgcn_s_barrier();
    compute(0);
    __builtin_amdgcn_s_barrier();
    if (kt2 < 7){
      stage(2*kt2+2, 0);
      asm volatile("s_waitcnt vmcnt(8)" ::: "memory");
    } else {
      asm volatile("s_waitcnt vmcnt(0)" ::: "memory");
    }
    __builtin_amdgcn_s_barrier();
    compute(1);
    __builtin_amdgcn_s_barrier();
  }

  #pragma unroll
  for (int mi=0;mi<4;mi++){
    #pragma unroll
    for (int ji=0;ji<4;ji++){
      int jg = j0 + wc*64 + ji*16 + lrow;
      int mg = m0 + wr*64 + mi*16 + kgrp*4;
      ushort4 st;
      st.x = f2bf(acc[mi][ji][0]);
      st.y = f2bf(acc[mi][ji][1]);
      st.z = f2bf(acc[mi][ji][2]);
      st.w = f2bf(acc[mi][ji][3]);
      *reinterpret_cast<ushort4*>(&Out[(size_t)jg*NN + mg]) = st;
    }
  }
}

// ---------- fused 6-term GEMM, 8-phase m201-style schedule ----------
// BM=256(m) x BN=192(j) x BK=64; 512 thr (8 waves: 2M x 4N); grid 256 = 1/CU.
// Per K-tile (group h): 4 phases (mh,kh), each {7 ds_read_b128 + 1-2 stage
// rounds -> counted vmcnt -> barrier -> 12 MFMA (setprio) -> barrier}.
// Half-tile staging into just-freed LDS regions; per-wave vmcnt(2)/(3) at
// q1/q3 (never 0 until the last 2 groups). Swizzle + XCD remap = R11-proven.
__global__ __launch_bounds__(512) void k_gemm6q(
    const u16* __restrict__ At, const u16* __restrict__ At2,
    const u16* __restrict__ U, const u16* __restrict__ Base,
    u16* __restrict__ Y){
  __shared__ __align__(16) u16 lds[2*28672];   // per buf (56KB): A 256x64 @0, B 192x64 @16384
  const int tid = threadIdx.x;
  const int w = tid >> 6, lane = tid & 63;
  const int lrow = lane & 15, kgrp = lane >> 4;
  const int wm = w & 1, wj = w >> 1;           // 2M x 4N
  const int swz = (lrow & 7) << 3;             // read-side XOR (u16 units)

  const int orig = blockIdx.x;
  const int wg = (orig & 7)*32 + (orig >> 3);  // bijective XCD remap (256 = 8*32)
  const int m0 = (wg & 3) * 256;
  const int j0 = (wg >> 2) * 192;

  const int srow = lane >> 3;
  const int skoff = ((lane & 7) << 3) ^ ((srow & 7) << 3);   // inverse-swizzled k-off

  // stage one 8KB round: A-half 'half' round r of tile T, or B round r of tile T
  #define SA(T, half, r) if ((T) < 96){                                        \
    int s_ = (T) >> 4, k0_ = ((T) & 15) << 6;                                  \
    const u16* Ab_ = ((s_ & 1) ? At2 : At) + (size_t)(s_ >> 1)*NN*NN;          \
    int ch_ = (half)*16 + (r)*8 + w;                                           \
    gll16(Ab_ + (size_t)(m0 + ch_*8 + srow)*1024 + k0_ + skoff,                \
          (u16*)lds + ((T)&1)*28672 + ch_*512); }
  #define SB(T, r) if ((T) < 96){                                              \
    int s_ = (T) >> 4, k0_ = ((T) & 15) << 6;                                  \
    int ch_ = (r)*8 + w;                                                       \
    gll16(U + (size_t)s_*HBE + (size_t)(j0 + ch_*8 + srow)*1024 + k0_ + skoff, \
          (u16*)lds + ((T)&1)*28672 + 16384 + ch_*512); }

  f32x4 acc[8][3];
  #pragma unroll
  for (int mi=0;mi<8;mi++)
    #pragma unroll
    for (int ji=0;ji<3;ji++)
      acc[mi][ji] = (f32x4){0.f,0.f,0.f,0.f};

  // prologue: tile0 A0(2) A1(r0) B(3); tile1 A0(2)
  SA(0,0,0) SA(0,0,1) SA(0,1,0) SB(0,0) SB(0,1) SB(0,2) SA(1,0,0) SA(1,0,1)
  asm volatile("s_waitcnt vmcnt(0)" ::: "memory");
  __builtin_amdgcn_s_barrier();

  #pragma unroll 1
  for (int h=0; h<96; ++h){
    const int c = h & 1;
    #pragma unroll
    for (int q=0; q<4; ++q){
      const int mh = q >> 1, kh = q & 1;
      // ds_read fragments for this phase (buf c)
      bf16x8 af[4], bv[3];
      #pragma unroll
      for (int mi=0;mi<4;mi++){
        int row = wm*128 + mh*64 + mi*16 + lrow;
        af[mi] = *reinterpret_cast<const bf16x8*>(
            &lds[c*28672 + row*64 + ((kh*32 + kgrp*8) ^ swz)]);
      }
      #pragma unroll
      for (int ji=0;ji<3;ji++){
        int rowb = wj*48 + ji*16 + lrow;
        bv[ji] = *reinterpret_cast<const bf16x8*>(
            &lds[c*28672 + 16384 + rowb*64 + ((kh*32 + kgrp*8) ^ swz)]);
      }
      // staged rounds (issue order matters for the counted vmcnt)
      if (q==0){ SA(h,1,1) SB(h+1,0) }
      else if (q==1){
        SB(h+1,1)
        if (h < 94) asm volatile("s_waitcnt vmcnt(2)" ::: "memory");
        else        asm volatile("s_waitcnt vmcnt(0)" ::: "memory");
      }
      else if (q==2){ SB(h+1,2) SA(h+2,0,0) }
      else {
        SA(h+1,1,0) SA(h+2,0,1)
        if (h < 94) asm volatile("s_waitcnt vmcnt(3)" ::: "memory");
        else        asm volatile("s_waitcnt vmcnt(0)" ::: "memory");
      }
      __builtin_amdgcn_s_barrier();
      __builtin_amdgcn_sched_barrier(0);
      __builtin_amdgcn_s_setprio(1);
      #pragma unroll
      for (int mi=0;mi<4;mi++)
        #pragma unroll
        for (int ji=0;ji<3;ji++)
          acc[mh*4+mi][ji] =
            __builtin_amdgcn_mfma_f32_16x16x32_bf16(af[mi], bv[ji], acc[mh*4+mi][ji], 0, 0, 0);
      __builtin_amdgcn_s_setprio(0);
      __builtin_amdgcn_s_barrier();
    }
  }
  #undef SA
  #undef SB

  #pragma unroll
  for (int mi=0;mi<8;mi++){
    #pragma unroll
    for (int ji=0;ji<3;ji++){
      int jg = j0 + wj*48 + ji*16 + lrow;
      int mg = m0 + wm*128 + mi*16 + kgrp*4;
      const ushort4 bv4 = *reinterpret_cast<const ushort4*>(&Base[(size_t)jg*NN + mg]);
      ushort4 st;
      st.x = f2bf(acc[mi][ji][0] + bf2f(bv4.x));
      st.y = f2bf(acc[mi][ji][1] + bf2f(bv4.y));
      st.z = f2bf(acc[mi][ji][2] + bf2f(bv4.z));
      st.w = f2bf(acc[mi][ji][3] + bf2f(bv4.w));
      *reinterpret_cast<ushort4*>(&Y[(size_t)jg*NN + mg]) = st;
    }
  }
}

// ---------- final channel mix (fallback path only) ----------
__global__ __launch_bounds__(256) void k_mix7(u16* zt_y,
    const u16* __restrict__ Db, const float* __restrict__ W,
    const float* __restrict__ bias){
  __shared__ u32 X[112][64];   // 28 KB
  int tid = threadIdx.x;
  int n0 = blockIdx.x*128;
  int bt = blockIdx.y;
  int b = bt / NT, t = bt - b*NT;
  int lane = tid & 63;
  int og = __builtin_amdgcn_readfirstlane(tid >> 6);

  float a0[8], a1[8];
  #pragma unroll
  for (int oo=0;oo<8;oo++){ float bv = bias[og*8+oo]; a0[oo]=bv; a1[oo]=bv; }

  #pragma unroll 1
  for (int chunk=0; chunk<2; ++chunk){
    if (chunk) __syncthreads();
    #pragma unroll
    for (int k=0;k<28;k++){
      int i = tid + k*256;
      int rl = i >> 6, col = i & 63;
      int r = chunk*112 + rl;
      int s = r >> 5, c = r & 31;
      const u16* src = (s==0) ? zt_y : (Db + (size_t)(s-1)*HBE);
      X[rl][col] = *reinterpret_cast<const u32*>(src + ((size_t)(b*NC + c)*NT + t)*NN + n0 + 2*col);
    }
    __syncthreads();
    #pragma unroll
    for (int cc=0; cc<112; ++cc){
      u32 xp = X[cc][lane];
      float xl = bflo(xp), xh = bfhi(xp);
      #pragma unroll
      for (int oo=0;oo<8;oo++){
        float w = W[(size_t)(og*8+oo)*TIN + chunk*112 + cc];
        a0[oo] += w*xl; a1[oo] += w*xh;
      }
    }
  }

  #pragma unroll
  for (int oo=0;oo<8;oo++){
    u32 pk = (u32)f2bf(a0[oo]) | ((u32)f2bf(a1[oo]) << 16);
    *reinterpret_cast<u32*>(zt_y + ((size_t)(b*NO + og*8+oo)*NT + t)*NN + n0 + 2*lane) = pk;
  }
}

// ---------- final transpose v2 (vectorized): y[b,o,n,t] = f32(Yb[(b*32+o)*12+t][n]) ----------
__global__ __launch_bounds__(256) void k_out3(const u16* __restrict__ Yb,
                                              float* __restrict__ y){
  __shared__ float tl[512][13];   // 26.6 KB
  int n0 = blockIdx.x*512;
  int bo = blockIdx.y;               // b*32 + o
  int tid = threadIdx.x;
  #pragma unroll
  for (int k=0;k<12;k++){
    u32 v = *reinterpret_cast<const u32*>(Yb + ((size_t)bo*NT + k)*NN + n0 + 2*tid);
    tl[2*tid][k]   = bflo(v);
    tl[2*tid+1][k] = bfhi(v);
  }
  __syncthreads();
  float* yp = y + ((size_t)bo*NN + n0)*NT;   // 6144 consecutive floats
  #pragma unroll
  for (int q=0;q<6;q++){
    int idx = tid + q*256;
    int e = idx*4;
    float4 v;
    v.x = tl[(e+0)/12][(e+0)%12];
    v.y = tl[(e+1)/12][(e+1)%12];
    v.z = tl[(e+2)/12][(e+2)%12];
    v.w = tl[(e+3)/12][(e+3)%12];
    *reinterpret_cast<float4*>(yp + e) = v;
  }
}

// ---------- final transpose (fallback path) ----------
__global__ __launch_bounds__(256) void k_out2(const u16* __restrict__ Yb,
                                              float* __restrict__ y){
  __shared__ float tl[256][13];
  int n0 = blockIdx.x*256;
  int bo = blockIdx.y;
  int tid = threadIdx.x;
  #pragma unroll
  for (int k=0;k<12;k++)
    tl[tid][k] = bf2f(Yb[((size_t)bo*NT + k)*NN + n0 + tid]);
  __syncthreads();
  float* yp = y + ((size_t)bo*NN + n0)*NT;
  #pragma unroll
  for (int k=0;k<12;k++){
    int i = k*256 + tid;
    yp[i] = tl[i/12][i%12];
  }
}

extern "C" void kernel_launch(void* const* d_in, const int* in_sizes, int n_in,
                              void* d_out, int out_size, void* d_ws, size_t ws_size,
                              hipStream_t stream){
  const float* x    = (const float*)d_in[0];
  const float* a0   = (const float*)d_in[1];
  const float* a1   = (const float*)d_in[2];
  const float* a2   = (const float*)d_in[3];
  const float* W    = (const float*)d_in[4];
  const float* bias = (const float*)d_in[5];
  float* y = (float*)d_out;
  (void)in_sizes; (void)n_in; (void)out_size;

  const size_t atB = (size_t)3*NN*NN*2;     // 6.29 MB
  const size_t ztB = HBE*2;                 // 25.17 MB
  const size_t need_fused = 2*atB + 8*ztB;  // 213.9 MB (R9-R13 verified available)

  if (ws_size >= need_fused){
    char* ws = (char*)d_ws;
    u16* At   = (u16*)ws;  ws += atB;
    u16* At2  = (u16*)ws;  ws += atB;
    u16* Zt   = (u16*)ws;  ws += ztB;       // holds Zc, then Y after k_gemm6q
    u16* U    = (u16*)ws;  ws += 6*ztB;
    u16* Base = (u16*)ws;  ws += ztB;
    u16* Ar   = Base;                        // dead after k_bgemm<0>

    k_prep_adj<<<dim3(32,32,3), dim3(32,8), 0, stream>>>(a0, a1, a2, At, Ar);
    k_bgemm<0><<<dim3(NN/128, NN/128, 3), 256, 0, stream>>>(At, Ar, At2, Zt, U);
    k_prep_x3<<<dim3(NN/64, NB), 256, 0, stream>>>(x, Zt);          // Zc
    k_pmix<<<dim3(2, NB*NT), 256, 0, stream>>>(Zt, W, bias, U, Base);
    k_gemm6q<<<256, 512, 0, stream>>>(At, At2, U, Base, Zt);        // Y over Zc
    k_out3<<<dim3(NN/512, NB*NO), 256, 0, stream>>>(Zt, y);
  } else {
    // fallback: two dependent batched GEMM dispatches + late mix
    char* ws = (char*)d_ws;
    u16* At  = (u16*)ws;  ws += atB;
    u16* Zt  = (u16*)ws;  ws += ztB;
    u16* Db  = (u16*)ws;  ws += 6*ztB;
    u16* Ar  = Db + 6*HBE - (size_t)3*NN*NN;

    k_prep_adj<<<dim3(32,32,3), dim3(32,8), 0, stream>>>(a0, a1, a2, At, Ar);
    k_prep_x2 <<<dim3(NN/64, NB*NC), 256, 0, stream>>>(x, Zt);
    k_bgemm<2><<<dim3(NJ/128, NN/128, 3), 256, 0, stream>>>(At, Ar, At, Zt, Db);
    k_bgemm<3><<<dim3(NJ/128, NN/128, 3), 256, 0, stream>>>(At, Ar, At, Zt, Db);
    k_mix7<<<dim3(NN/128, NB*NT), 256, 0, stream>>>(Zt, Db, W, bias);
    k_out2<<<dim3(NN/256, NB*NO), 256, 0, stream>>>(Zt, y);
  }
}

// Round 15
// 271.333 us; speedup vs baseline: 1.1619x; 1.1318x over previous
//
#include <hip/hip_runtime.h>
#include <stdint.h>

#define NB 32      // batch
#define NC 32      // in channels
#define NN 1024    // nodes
#define NT 12      // time
#define NJ (NB*NC*NT)  // 12288
#define NO 32      // out channels
#define TIN 224    // (2*3+1)*32
#define HBE ((size_t)NJ*NN)   // elements per [j][n] buffer

typedef __attribute__((ext_vector_type(8))) __bf16 bf16x8;
typedef __attribute__((ext_vector_type(4))) float f32x4;
typedef unsigned short u16;
typedef unsigned int u32;

__device__ __forceinline__ u16 f2bf(float f){
  u32 u = __float_as_uint(f);
  u32 r = (u + 0x7FFFu + ((u >> 16) & 1u)) >> 16;   // RNE
  return (u16)r;
}
__device__ __forceinline__ float bf2f(u16 h){
  return __uint_as_float(((u32)h) << 16);
}
__device__ __forceinline__ float bflo(u32 v){ return __uint_as_float(v << 16); }
__device__ __forceinline__ float bfhi(u32 v){ return __uint_as_float(v & 0xFFFF0000u); }

typedef const __attribute__((address_space(1))) u32* gp_t;
typedef __attribute__((address_space(3))) u32* lp_t;
__device__ __forceinline__ void gll16(const void* g, void* l){
  __builtin_amdgcn_global_load_lds((gp_t)g, (lp_t)l, 16, 0, 0);
}

// ---------- prep adj: At[z][m][n] = bf16(adj_z[n][m]) ; Ar[z][n][m] = bf16(adj_z[n][m]) ----------
__global__ __launch_bounds__(256) void k_prep_adj(const float* __restrict__ a0,
      const float* __restrict__ a1, const float* __restrict__ a2,
      u16* __restrict__ At, u16* __restrict__ Ar){
  __shared__ float tile[32][33];
  const float* A = (blockIdx.z==0) ? a0 : (blockIdx.z==1 ? a1 : a2);
  int n0 = blockIdx.x*32, m0 = blockIdx.y*32;
  int tx = threadIdx.x, ty = threadIdx.y;  // block (32,8)
  u16* dstR = Ar + (size_t)blockIdx.z*NN*NN;
  #pragma unroll
  for (int r=0;r<4;r++){
    float v = A[(size_t)(n0 + ty + 8*r)*NN + m0 + tx];
    tile[ty + 8*r][tx] = v;
    dstR[(size_t)(n0 + ty + 8*r)*NN + m0 + tx] = f2bf(v);
  }
  __syncthreads();
  u16* dst = At + (size_t)blockIdx.z*NN*NN;
  #pragma unroll
  for (int r=0;r<4;r++)
    dst[(size_t)(m0 + ty + 8*r)*NN + n0 + tx] = f2bf(tile[tx][ty + 8*r]);
}

// ---------- prep x (fallback layout): Zt[j][n] = bf16(x[p,n,t]) ----------
__global__ __launch_bounds__(256) void k_prep_x2(const float* __restrict__ x, u16* __restrict__ Zt){
  __shared__ float tl[64][13];
  int p = blockIdx.y, n0 = blockIdx.x*64;
  const float* xp = x + (size_t)p*NN*NT + (size_t)n0*NT;
  int tid = threadIdx.x;
  #pragma unroll
  for (int k=0;k<3;k++){
    int e = tid + k*256;
    float v = xp[e];
    tl[e/12][e%12] = v;
  }
  __syncthreads();
  #pragma unroll
  for (int k=0;k<3;k++){
    int e = tid + k*256;
    int t = e >> 6, nn = e & 63;
    Zt[((size_t)p*NT + t)*NN + n0 + nn] = f2bf(tl[nn][t]);
  }
}

// ---------- prep x (primary): Zc[(b*12+t)][n][c] = bf16(x[b,c,n,t]) ----------
__global__ __launch_bounds__(256) void k_prep_x3(const float* __restrict__ x,
                                                 u16* __restrict__ Zc){
  __shared__ u16 T[32*780];   // [c][n 64][t 12] u16, 49.9 KB
  int tid = threadIdx.x;
  int n0 = blockIdx.x*64, b = blockIdx.y;
  #pragma unroll
  for (int k=0;k<24;k++){
    int idx = tid + k*256;            // 6144 float4 per block
    int c = idx / 192, f = idx - c*192;
    float4 v = *reinterpret_cast<const float4*>(
        x + ((size_t)(b*NC + c)*NN + n0)*NT + f*4);
    #pragma unroll
    for (int j=0;j<4;j++){
      int e = f*4 + j;
      int nl = e / 12, tt = e - nl*12;
      float fv = (j==0)?v.x:(j==1)?v.y:(j==2)?v.z:v.w;
      T[c*780 + nl*12 + tt] = f2bf(fv);
    }
  }
  __syncthreads();
  #pragma unroll
  for (int k=0;k<48;k++){
    int i = tid + k*256;              // 12288 u32 per block
    int tt = i >> 10, rem = i & 1023, nl = rem >> 4, cp = rem & 15;
    u32 lo = T[(2*cp)*780 + nl*12 + tt];
    u32 hi = T[(2*cp+1)*780 + nl*12 + tt];
    *reinterpret_cast<u32*>(Zc + (((size_t)(b*NT + tt)*NN + n0 + nl) << 5) + 2*cp)
        = lo | (hi << 16);
  }
}

// ---------- MFMA premix (R11-proven) ----------
__global__ __launch_bounds__(256) void k_pmix(const u16* __restrict__ Zc,
    const float* __restrict__ W, const float* __restrict__ bias,
    u16* __restrict__ U, u16* __restrict__ Base){
  __shared__ __align__(16) u16 Xl[16384];   // 512 n x 32 c, 32 KB
  int tid = threadIdx.x;
  int w = tid >> 6, lane = tid & 63;
  int lrow = lane & 15, kgrp = lane >> 4;
  int nh = blockIdx.x;               // n-half (512)
  int bt = blockIdx.y;               // b*12 + t
  int b = bt / NT, t = bt - b*NT;

  const u16* src = Zc + ((size_t)bt*NN + (size_t)nh*512)*32;
  #pragma unroll
  for (int k=0;k<8;k++){
    int chunk = w*8 + k;
    gll16(src + (size_t)chunk*512 + lane*8, (u16*)Xl + chunk*512);
  }

  bf16x8 af[7][2];
  #pragma unroll
  for (int g=0; g<7; g++){
    #pragma unroll
    for (int ot=0; ot<2; ot++){
      const float* wr = W + (size_t)(ot*16 + lrow)*TIN + g*32 + kgrp*8;
      float4 wa = *reinterpret_cast<const float4*>(wr);
      float4 wb = *reinterpret_cast<const float4*>(wr + 4);
      u32 tmp[4];
      tmp[0] = (u32)f2bf(wa.x) | ((u32)f2bf(wa.y) << 16);
      tmp[1] = (u32)f2bf(wa.z) | ((u32)f2bf(wa.w) << 16);
      tmp[2] = (u32)f2bf(wb.x) | ((u32)f2bf(wb.y) << 16);
      tmp[3] = (u32)f2bf(wb.z) | ((u32)f2bf(wb.w) << 16);
      af[g][ot] = *reinterpret_cast<bf16x8*>(tmp);
    }
  }
  float4 bias4[2];
  #pragma unroll
  for (int ot=0; ot<2; ot++)
    bias4[ot] = *reinterpret_cast<const float4*>(bias + ot*16 + kgrp*4);

  __syncthreads();

  #pragma unroll
  for (int nt=0; nt<8; nt++){
    int row = w*128 + nt*16 + lrow;
    int n = nh*512 + row;
    bf16x8 bfr = *reinterpret_cast<const bf16x8*>(&Xl[row*32 + kgrp*8]);
    #pragma unroll
    for (int g=0; g<7; g++){
      u16* dstb = (g==0) ? Base : (U + (size_t)(g-1)*HBE);
      #pragma unroll
      for (int ot=0; ot<2; ot++){
        f32x4 acc = (f32x4){0.f,0.f,0.f,0.f};
        acc = __builtin_amdgcn_mfma_f32_16x16x32_bf16(af[g][ot], bfr, acc, 0, 0, 0);
        if (g==0){
          acc[0] += bias4[ot].x; acc[1] += bias4[ot].y;
          acc[2] += bias4[ot].z; acc[3] += bias4[ot].w;
        }
        int o = ot*16 + kgrp*4;
        size_t rb = ((size_t)(b*NO + o)*NT + t)*NN + n;
        dstb[rb]                    = f2bf(acc[0]);
        dstb[rb + (size_t)NT*NN]    = f2bf(acc[1]);
        dstb[rb + (size_t)2*NT*NN]  = f2bf(acc[2]);
        dstb[rb + (size_t)3*NT*NN]  = f2bf(acc[3]);
      }
    }
  }
}

// ---------- batched GEMM, 2-phase double-buffered (fallback + At2), MODE0/2/3 ----------
#define BKK 64
template<int MODE>
__global__ __launch_bounds__(256) void k_bgemm(
    const u16* __restrict__ At, const u16* __restrict__ Ar,
    u16* __restrict__ At2, const u16* __restrict__ Zt,
    u16* __restrict__ Db){
  __shared__ __align__(16) u16 As[2][128*BKK];
  __shared__ __align__(16) u16 Bs[2][128*BKK];
  int tid = threadIdx.x;
  int w = tid >> 6, lane = tid & 63;
  int z = blockIdx.z;
  int m0 = blockIdx.y * 128, j0 = blockIdx.x * 128;
  int wr = w >> 1, wc = w & 1;
  int lrow = lane & 15, kgrp = lane >> 4;
  int lr8 = lane >> 3, lc8 = lane & 7;

  const u16* Amat; const u16* Bmat; u16* Out;
  if (MODE==0){
    Amat = Ar + (size_t)z*NN*NN; Bmat = At + (size_t)z*NN*NN; Out = At2 + (size_t)z*NN*NN;
  } else if (MODE==2){
    Amat = At + (size_t)z*NN*NN; Bmat = Zt; Out = Db + (size_t)(2*z)*HBE;
  } else {
    Amat = At + (size_t)z*NN*NN; Bmat = Db + (size_t)(2*z)*HBE; Out = Db + (size_t)(2*z+1)*HBE;
  }

  f32x4 acc[4][4];
  #pragma unroll
  for (int i=0;i<4;i++)
    #pragma unroll
    for (int jj=0;jj<4;jj++)
      acc[i][jj] = (f32x4){0.f,0.f,0.f,0.f};

  const u16* Abase = Amat + (size_t)m0*1024;
  const u16* Bbase = Bmat + (size_t)j0*1024;

  auto stage = [&](int kt, int d){
    int k0 = kt*BKK;
    #pragma unroll
    for (int i=0;i<4;i++){
      int q = w*4 + i;
      int row = q*8 + lr8;
      gll16(Abase + (size_t)row*1024 + k0 + lc8*8, (u16*)&As[d][0] + q*512);
      gll16(Bbase + (size_t)row*1024 + k0 + lc8*8, (u16*)&Bs[d][0] + q*512);
    }
  };
  auto compute = [&](int d){
    #pragma unroll
    for (int kk=0; kk<2; ++kk){
      bf16x8 af[4], bfr[4];
      #pragma unroll
      for (int mi=0;mi<4;mi++)
        af[mi] = *reinterpret_cast<const bf16x8*>(&As[d][(wr*64+mi*16+lrow)*BKK + kk*32 + kgrp*8]);
      #pragma unroll
      for (int ji=0;ji<4;ji++)
        bfr[ji] = *reinterpret_cast<const bf16x8*>(&Bs[d][(wc*64+ji*16+lrow)*BKK + kk*32 + kgrp*8]);
      #pragma unroll
      for (int mi=0;mi<4;mi++)
        #pragma unroll
        for (int ji=0;ji<4;ji++)
          acc[mi][ji] = __builtin_amdgcn_mfma_f32_16x16x32_bf16(af[mi], bfr[ji], acc[mi][ji], 0, 0, 0);
    }
  };

  stage(0, 0);
  #pragma unroll 1
  for (int kt2=0; kt2<8; ++kt2){
    stage(2*kt2+1, 1);
    asm volatile("s_waitcnt vmcnt(8)" ::: "memory");
    __builtin_amdgcn_s_barrier();
    compute(0);
    __builtin_amdgcn_s_barrier();
    if (kt2 < 7){
      stage(2*kt2+2, 0);
      asm volatile("s_waitcnt vmcnt(8)" ::: "memory");
    } else {
      asm volatile("s_waitcnt vmcnt(0)" ::: "memory");
    }
    __builtin_amdgcn_s_barrier();
    compute(1);
    __builtin_amdgcn_s_barrier();
  }

  #pragma unroll
  for (int mi=0;mi<4;mi++){
    #pragma unroll
    for (int ji=0;ji<4;ji++){
      int jg = j0 + wc*64 + ji*16 + lrow;
      int mg = m0 + wr*64 + mi*16 + kgrp*4;
      ushort4 st;
      st.x = f2bf(acc[mi][ji][0]);
      st.y = f2bf(acc[mi][ji][1]);
      st.z = f2bf(acc[mi][ji][2]);
      st.w = f2bf(acc[mi][ji][3]);
      *reinterpret_cast<ushort4*>(&Out[(size_t)jg*NN + mg]) = st;
    }
  }
}

// ---------- fused 6-term GEMM (R11-proven main loop) + fused f32 transpose epilogue ----------
// Main loop identical to R11's k_gemm6p (256x192, 8 waves, 2-barrier, stage-spread,
// counted vmcnt(2), swizzle T2 both-sides, setprio, XCD remap). Epilogue writes
// y[b,o,n,t] f32 DIRECTLY: per round r, waves wj==r scatter acc+Base into LDS as
// [bo][n][t] (8 bo x 3072 f32 = 96KB, reusing the staging LDS), then all 512
// threads write 12 coalesced float4 each. Eliminates the separate k_out3 pass.
__global__ __launch_bounds__(512) void k_gemm6p(
    const u16* __restrict__ At, const u16* __restrict__ At2,
    const u16* __restrict__ U, const u16* __restrict__ Base,
    float* __restrict__ y){
  __shared__ __align__(16) u16 lds[2][28672];   // per buf: A 256x64 @0, B 192x64 @16384
  const int tid = threadIdx.x;
  const int w = tid >> 6, lane = tid & 63;
  const int lrow = lane & 15, kgrp = lane >> 4;
  const int wm = w & 3, wj = w >> 2;
  const int swz = (lrow & 7) << 3;           // read-side XOR (u16 units, 16B slots)

  const int orig = blockIdx.x;
  const int wg = (orig & 7)*32 + (orig >> 3);  // bijective XCD remap (256 = 8*32)
  const int m0 = (wg >> 6) * 256;
  const int j0 = (wg & 63) * 192;

  const int srow = lane >> 3;
  const int skoff = ((lane & 7) << 3) ^ ((srow & 7) << 3);   // inverse-swizzled k-off
  size_t rowoff[7]; int ldsoff[7]; bool isA[7];
  #pragma unroll
  for (int i=0;i<7;i++){
    int c = w*7 + i;
    if (c < 32){
      int row = c*8 + srow;
      isA[i] = true;  rowoff[i] = (size_t)(m0 + row)*1024 + skoff;  ldsoff[i] = c*512;
    } else {
      int cb = c - 32;
      int row = cb*8 + srow;
      isA[i] = false; rowoff[i] = (size_t)(j0 + row)*1024 + skoff;  ldsoff[i] = 16384 + cb*512;
    }
  }

  #define STAGE(t, i) {                                                        \
    int s_ = (t) >> 4;                                                         \
    int k0_ = ((t) & 15) << 6;                                                 \
    const u16* Ab_ = ((s_ & 1) ? At2 : At) + (size_t)(s_ >> 1)*NN*NN;          \
    const u16* src_ = (isA[i] ? Ab_ : (U + (size_t)s_*HBE)) + rowoff[i] + k0_; \
    gll16(src_, &lds[(t) & 1][ldsoff[i]]); }

  f32x4 acc[4][6];
  #pragma unroll
  for (int mi=0;mi<4;mi++)
    #pragma unroll
    for (int ji=0;ji<6;ji++)
      acc[mi][ji] = (f32x4){0.f,0.f,0.f,0.f};

  #pragma unroll
  for (int i=0;i<7;i++) STAGE(0, i)

  #pragma unroll 1
  for (int t=0; t<96; ++t){
    const int d = t & 1;
    if (t < 95){
      STAGE(t+1, 0) STAGE(t+1, 1)
      asm volatile("s_waitcnt vmcnt(2)" ::: "memory");
    } else {
      asm volatile("s_waitcnt vmcnt(0)" ::: "memory");
    }
    __builtin_amdgcn_s_barrier();
    __builtin_amdgcn_sched_barrier(0);

    bf16x8 bf[6][2];
    #pragma unroll
    for (int p=0;p<4;p++){
      if (t < 95){
        if (p==0){ STAGE(t+1, 2) STAGE(t+1, 3) }
        else if (p==1){ STAGE(t+1, 4) STAGE(t+1, 5) }
        else if (p==2){ STAGE(t+1, 6) }
      }
      if (p==0){
        #pragma unroll
        for (int ji=0;ji<6;ji++){
          int row = wj*96 + ji*16 + lrow;
          #pragma unroll
          for (int kk=0;kk<2;kk++)
            bf[ji][kk] = *reinterpret_cast<const bf16x8*>(
              &lds[d][16384 + row*64 + ((kk*32 + kgrp*8) ^ swz)]);
        }
      }
      bf16x8 af0, af1;
      {
        int row = wm*64 + p*16 + lrow;
        af0 = *reinterpret_cast<const bf16x8*>(&lds[d][row*64 + ((kgrp*8) ^ swz)]);
        af1 = *reinterpret_cast<const bf16x8*>(&lds[d][row*64 + ((32 + kgrp*8) ^ swz)]);
      }
      __builtin_amdgcn_s_setprio(1);
      #pragma unroll
      for (int ji=0;ji<6;ji++){
        acc[p][ji] = __builtin_amdgcn_mfma_f32_16x16x32_bf16(af0, bf[ji][0], acc[p][ji], 0, 0, 0);
        acc[p][ji] = __builtin_amdgcn_mfma_f32_16x16x32_bf16(af1, bf[ji][1], acc[p][ji], 0, 0, 0);
      }
      __builtin_amdgcn_s_setprio(0);
    }
    __builtin_amdgcn_s_barrier();   // all waves done reading buf d before t+2 stages hit it
  }
  #undef STAGE

  // ---- fused transpose epilogue: y[bo][n][t] f32, via LDS, fully coalesced ----
  float* ldsf = (float*)&lds[0][0];           // 96 KB of the 112 KB staging LDS
  const int bo0 = j0 / NT;                    // j0 % 12 == 0
  #pragma unroll 1
  for (int r=0; r<2; ++r){
    if (r) __syncthreads();                   // round-0 readers done before round-1 writers
    if (wj == r){
      #pragma unroll
      for (int ji=0;ji<6;ji++){
        int jl = ji*16 + lrow;                // 0..95 within this wj half
        int bo8 = jl / NT, tt = jl - bo8*NT;  // bo8 in 0..7
        int jg = j0 + r*96 + jl;
        #pragma unroll
        for (int mi=0;mi<4;mi++){
          int nl = wm*64 + mi*16 + kgrp*4;
          const ushort4 bv = *reinterpret_cast<const ushort4*>(&Base[(size_t)jg*NN + m0 + nl]);
          float* p = ldsf + bo8*3072 + nl*NT + tt;
          p[0]  = acc[mi][ji][0] + bf2f(bv.x);
          p[12] = acc[mi][ji][1] + bf2f(bv.y);
          p[24] = acc[mi][ji][2] + bf2f(bv.z);
          p[36] = acc[mi][ji][3] + bf2f(bv.w);
        }
      }
    }
    __syncthreads();                          // writers done before readers
    #pragma unroll
    for (int q=0;q<12;q++){
      int idx = tid + q*512;                  // 6144 float4 per round
      int bo8 = idx / 768, off = (idx - bo8*768)*4;
      *reinterpret_cast<float4*>(y + ((size_t)(bo0 + r*8 + bo8))*(NN*NT) + (size_t)m0*NT + off)
        = *reinterpret_cast<const float4*>(ldsf + bo8*3072 + off);
    }
  }
}

// ---------- final channel mix (fallback path only) ----------
__global__ __launch_bounds__(256) void k_mix7(u16* zt_y,
    const u16* __restrict__ Db, const float* __restrict__ W,
    const float* __restrict__ bias){
  __shared__ u32 X[112][64];   // 28 KB
  int tid = threadIdx.x;
  int n0 = blockIdx.x*128;
  int bt = blockIdx.y;
  int b = bt / NT, t = bt - b*NT;
  int lane = tid & 63;
  int og = __builtin_amdgcn_readfirstlane(tid >> 6);

  float a0[8], a1[8];
  #pragma unroll
  for (int oo=0;oo<8;oo++){ float bv = bias[og*8+oo]; a0[oo]=bv; a1[oo]=bv; }

  #pragma unroll 1
  for (int chunk=0; chunk<2; ++chunk){
    if (chunk) __syncthreads();
    #pragma unroll
    for (int k=0;k<28;k++){
      int i = tid + k*256;
      int rl = i >> 6, col = i & 63;
      int r = chunk*112 + rl;
      int s = r >> 5, c = r & 31;
      const u16* src = (s==0) ? zt_y : (Db + (size_t)(s-1)*HBE);
      X[rl][col] = *reinterpret_cast<const u32*>(src + ((size_t)(b*NC + c)*NT + t)*NN + n0 + 2*col);
    }
    __syncthreads();
    #pragma unroll
    for (int cc=0; cc<112; ++cc){
      u32 xp = X[cc][lane];
      float xl = bflo(xp), xh = bfhi(xp);
      #pragma unroll
      for (int oo=0;oo<8;oo++){
        float w = W[(size_t)(og*8+oo)*TIN + chunk*112 + cc];
        a0[oo] += w*xl; a1[oo] += w*xh;
      }
    }
  }

  #pragma unroll
  for (int oo=0;oo<8;oo++){
    u32 pk = (u32)f2bf(a0[oo]) | ((u32)f2bf(a1[oo]) << 16);
    *reinterpret_cast<u32*>(zt_y + ((size_t)(b*NO + og*8+oo)*NT + t)*NN + n0 + 2*lane) = pk;
  }
}

// ---------- final transpose (fallback path) ----------
__global__ __launch_bounds__(256) void k_out2(const u16* __restrict__ Yb,
                                              float* __restrict__ y){
  __shared__ float tl[256][13];
  int n0 = blockIdx.x*256;
  int bo = blockIdx.y;
  int tid = threadIdx.x;
  #pragma unroll
  for (int k=0;k<12;k++)
    tl[tid][k] = bf2f(Yb[((size_t)bo*NT + k)*NN + n0 + tid]);
  __syncthreads();
  float* yp = y + ((size_t)bo*NN + n0)*NT;
  #pragma unroll
  for (int k=0;k<12;k++){
    int i = k*256 + tid;
    yp[i] = tl[i/12][i%12];
  }
}

extern "C" void kernel_launch(void* const* d_in, const int* in_sizes, int n_in,
                              void* d_out, int out_size, void* d_ws, size_t ws_size,
                              hipStream_t stream){
  const float* x    = (const float*)d_in[0];
  const float* a0   = (const float*)d_in[1];
  const float* a1   = (const float*)d_in[2];
  const float* a2   = (const float*)d_in[3];
  const float* W    = (const float*)d_in[4];
  const float* bias = (const float*)d_in[5];
  float* y = (float*)d_out;
  (void)in_sizes; (void)n_in; (void)out_size;

  const size_t atB = (size_t)3*NN*NN*2;     // 6.29 MB
  const size_t ztB = HBE*2;                 // 25.17 MB
  const size_t need_fused = 2*atB + 8*ztB;  // 213.9 MB (R9-R14 verified available)

  if (ws_size >= need_fused){
    char* ws = (char*)d_ws;
    u16* At   = (u16*)ws;  ws += atB;
    u16* At2  = (u16*)ws;  ws += atB;
    u16* Zt   = (u16*)ws;  ws += ztB;       // holds Zc
    u16* U    = (u16*)ws;  ws += 6*ztB;
    u16* Base = (u16*)ws;  ws += ztB;
    u16* Ar   = Base;                        // dead after k_bgemm<0>

    k_prep_adj<<<dim3(32,32,3), dim3(32,8), 0, stream>>>(a0, a1, a2, At, Ar);
    k_bgemm<0><<<dim3(NN/128, NN/128, 3), 256, 0, stream>>>(At, Ar, At2, Zt, U);
    k_prep_x3<<<dim3(NN/64, NB), 256, 0, stream>>>(x, Zt);          // Zc
    k_pmix<<<dim3(2, NB*NT), 256, 0, stream>>>(Zt, W, bias, U, Base);
    k_gemm6p<<<256, 512, 0, stream>>>(At, At2, U, Base, y);         // writes y directly
  } else {
    // fallback: two dependent batched GEMM dispatches + late mix
    char* ws = (char*)d_ws;
    u16* At  = (u16*)ws;  ws += atB;
    u16* Zt  = (u16*)ws;  ws += ztB;
    u16* Db  = (u16*)ws;  ws += 6*ztB;
    u16* Ar  = Db + 6*HBE - (size_t)3*NN*NN;

    k_prep_adj<<<dim3(32,32,3), dim3(32,8), 0, stream>>>(a0, a1, a2, At, Ar);
    k_prep_x2 <<<dim3(NN/64, NB*NC), 256, 0, stream>>>(x, Zt);
    k_bgemm<2><<<dim3(NJ/128, NN/128, 3), 256, 0, stream>>>(At, Ar, At, Zt, Db);
    k_bgemm<3><<<dim3(NJ/128, NN/128, 3), 256, 0, stream>>>(At, Ar, At, Zt, Db);
    k_mix7<<<dim3(NN/128, NB*NT), 256, 0, stream>>>(Zt, Db, W, bias);
    k_out2<<<dim3(NN/256, NB*NO), 256, 0, stream>>>(Zt, y);
  }
}

// Round 16
// 220.238 us; speedup vs baseline: 1.4315x; 1.2320x over previous
//
#include <hip/hip_runtime.h>
#include <stdint.h>

#define NB 32      // batch
#define NC 32      // in channels
#define NN 1024    // nodes
#define NT 12      // time
#define NJ (NB*NC*NT)  // 12288
#define NO 32      // out channels
#define TIN 224    // (2*3+1)*32
#define HBE ((size_t)NJ*NN)   // elements per [j][n] buffer

typedef __attribute__((ext_vector_type(8))) __bf16 bf16x8;
typedef __attribute__((ext_vector_type(4))) float f32x4;
typedef unsigned short u16;
typedef unsigned int u32;

__device__ __forceinline__ u16 f2bf(float f){
  u32 u = __float_as_uint(f);
  u32 r = (u + 0x7FFFu + ((u >> 16) & 1u)) >> 16;   // RNE
  return (u16)r;
}
__device__ __forceinline__ float bf2f(u16 h){
  return __uint_as_float(((u32)h) << 16);
}
__device__ __forceinline__ float bflo(u32 v){ return __uint_as_float(v << 16); }
__device__ __forceinline__ float bfhi(u32 v){ return __uint_as_float(v & 0xFFFF0000u); }

typedef const __attribute__((address_space(1))) u32* gp_t;
typedef __attribute__((address_space(3))) u32* lp_t;
__device__ __forceinline__ void gll16(const void* g, void* l){
  __builtin_amdgcn_global_load_lds((gp_t)g, (lp_t)l, 16, 0, 0);
}

// ---------- prep adj: At[z][m][n] = bf16(adj_z[n][m]) ; Ar[z][n][m] = bf16(adj_z[n][m]) ----------
__global__ __launch_bounds__(256) void k_prep_adj(const float* __restrict__ a0,
      const float* __restrict__ a1, const float* __restrict__ a2,
      u16* __restrict__ At, u16* __restrict__ Ar){
  __shared__ float tile[32][33];
  const float* A = (blockIdx.z==0) ? a0 : (blockIdx.z==1 ? a1 : a2);
  int n0 = blockIdx.x*32, m0 = blockIdx.y*32;
  int tx = threadIdx.x, ty = threadIdx.y;  // block (32,8)
  u16* dstR = Ar + (size_t)blockIdx.z*NN*NN;
  #pragma unroll
  for (int r=0;r<4;r++){
    float v = A[(size_t)(n0 + ty + 8*r)*NN + m0 + tx];
    tile[ty + 8*r][tx] = v;
    dstR[(size_t)(n0 + ty + 8*r)*NN + m0 + tx] = f2bf(v);
  }
  __syncthreads();
  u16* dst = At + (size_t)blockIdx.z*NN*NN;
  #pragma unroll
  for (int r=0;r<4;r++)
    dst[(size_t)(m0 + ty + 8*r)*NN + n0 + tx] = f2bf(tile[tx][ty + 8*r]);
}

// ---------- prep x (fallback layout): Zt[j][n] = bf16(x[p,n,t]) ----------
__global__ __launch_bounds__(256) void k_prep_x2(const float* __restrict__ x, u16* __restrict__ Zt){
  __shared__ float tl[64][13];
  int p = blockIdx.y, n0 = blockIdx.x*64;
  const float* xp = x + (size_t)p*NN*NT + (size_t)n0*NT;
  int tid = threadIdx.x;
  #pragma unroll
  for (int k=0;k<3;k++){
    int e = tid + k*256;
    float v = xp[e];
    tl[e/12][e%12] = v;
  }
  __syncthreads();
  #pragma unroll
  for (int k=0;k<3;k++){
    int e = tid + k*256;
    int t = e >> 6, nn = e & 63;
    Zt[((size_t)p*NT + t)*NN + n0 + nn] = f2bf(tl[nn][t]);
  }
}

// ---------- fused prep_x + premix: per (b, 64n) block, all 12 t ----------
// Loads x[b, :, n0..n0+63, :] coalesced (768-float spans), transposes in LDS to
// [t][n][c] (pitch 40 u16: 16B-aligned rows, spread banks), then MFMA premix:
// U[s] = W[:, (s+1)*32..] . x~ (s=0..5) bf16; Base = W[:,0..31].x~ + bias.
// Numerically identical to the former prep_x3 + k_pmix pair.
__global__ __launch_bounds__(256) void k_pmix2(const float* __restrict__ x,
    const float* __restrict__ W, const float* __restrict__ bias,
    u16* __restrict__ U, u16* __restrict__ Base){
  __shared__ __align__(16) u16 X[12*64*40];   // [t][nl][c pitch 40] = 60 KB
  int tid = threadIdx.x;
  int n0 = blockIdx.x*64, b = blockIdx.y;

  #pragma unroll
  for (int k=0;k<24;k++){
    int idx = tid + k*256;            // 6144 float4 per block
    int c = idx / 192, f = idx - c*192;
    float4 v = *reinterpret_cast<const float4*>(
        x + ((size_t)(b*NC + c)*NN + n0)*NT + f*4);
    #pragma unroll
    for (int j=0;j<4;j++){
      int e = f*4 + j;
      int nl = e / 12, tt = e - nl*12;
      float fv = (j==0)?v.x:(j==1)?v.y:(j==2)?v.z:v.w;
      X[(tt*64 + nl)*40 + c] = f2bf(fv);
    }
  }

  int lane = tid & 63, w = tid >> 6;
  int lrow = lane & 15, kgrp = lane >> 4;

  // A-fragments from W: af[grp][ot], lane = (o=ot*16+lrow, c=kgrp*8..+7)
  bf16x8 af[7][2];
  #pragma unroll
  for (int g=0; g<7; g++){
    #pragma unroll
    for (int ot=0; ot<2; ot++){
      const float* wr = W + (size_t)(ot*16 + lrow)*TIN + g*32 + kgrp*8;
      float4 wa = *reinterpret_cast<const float4*>(wr);
      float4 wb = *reinterpret_cast<const float4*>(wr + 4);
      u32 tmp[4];
      tmp[0] = (u32)f2bf(wa.x) | ((u32)f2bf(wa.y) << 16);
      tmp[1] = (u32)f2bf(wa.z) | ((u32)f2bf(wa.w) << 16);
      tmp[2] = (u32)f2bf(wb.x) | ((u32)f2bf(wb.y) << 16);
      tmp[3] = (u32)f2bf(wb.z) | ((u32)f2bf(wb.w) << 16);
      af[g][ot] = *reinterpret_cast<bf16x8*>(tmp);
    }
  }
  float4 bias4[2];
  #pragma unroll
  for (int ot=0; ot<2; ot++)
    bias4[ot] = *reinterpret_cast<const float4*>(bias + ot*16 + kgrp*4);

  __syncthreads();

  #pragma unroll 1
  for (int t=0; t<12; ++t){
    bf16x8 bfr = *reinterpret_cast<const bf16x8*>(
        &X[((t*64) + w*16 + lrow)*40 + kgrp*8]);
    #pragma unroll
    for (int g=0; g<7; g++){
      u16* dstb = (g==0) ? Base : (U + (size_t)(g-1)*HBE);
      #pragma unroll
      for (int ot=0; ot<2; ot++){
        f32x4 acc = (f32x4){0.f,0.f,0.f,0.f};
        acc = __builtin_amdgcn_mfma_f32_16x16x32_bf16(af[g][ot], bfr, acc, 0, 0, 0);
        if (g==0){
          acc[0] += bias4[ot].x; acc[1] += bias4[ot].y;
          acc[2] += bias4[ot].z; acc[3] += bias4[ot].w;
        }
        int o = ot*16 + kgrp*4;
        size_t rb = ((size_t)(b*NO + o)*NT + t)*NN + n0 + w*16 + lrow;
        dstb[rb]                    = f2bf(acc[0]);
        dstb[rb + (size_t)NT*NN]    = f2bf(acc[1]);
        dstb[rb + (size_t)2*NT*NN]  = f2bf(acc[2]);
        dstb[rb + (size_t)3*NT*NN]  = f2bf(acc[3]);
      }
    }
  }
}

// ---------- batched GEMM, 2-phase double-buffered (fallback + At2), MODE0/2/3 ----------
#define BKK 64
template<int MODE>
__global__ __launch_bounds__(256) void k_bgemm(
    const u16* __restrict__ At, const u16* __restrict__ Ar,
    u16* __restrict__ At2, const u16* __restrict__ Zt,
    u16* __restrict__ Db){
  __shared__ __align__(16) u16 As[2][128*BKK];
  __shared__ __align__(16) u16 Bs[2][128*BKK];
  int tid = threadIdx.x;
  int w = tid >> 6, lane = tid & 63;
  int z = blockIdx.z;
  int m0 = blockIdx.y * 128, j0 = blockIdx.x * 128;
  int wr = w >> 1, wc = w & 1;
  int lrow = lane & 15, kgrp = lane >> 4;
  int lr8 = lane >> 3, lc8 = lane & 7;

  const u16* Amat; const u16* Bmat; u16* Out;
  if (MODE==0){
    Amat = Ar + (size_t)z*NN*NN; Bmat = At + (size_t)z*NN*NN; Out = At2 + (size_t)z*NN*NN;
  } else if (MODE==2){
    Amat = At + (size_t)z*NN*NN; Bmat = Zt; Out = Db + (size_t)(2*z)*HBE;
  } else {
    Amat = At + (size_t)z*NN*NN; Bmat = Db + (size_t)(2*z)*HBE; Out = Db + (size_t)(2*z+1)*HBE;
  }

  f32x4 acc[4][4];
  #pragma unroll
  for (int i=0;i<4;i++)
    #pragma unroll
    for (int jj=0;jj<4;jj++)
      acc[i][jj] = (f32x4){0.f,0.f,0.f,0.f};

  const u16* Abase = Amat + (size_t)m0*1024;
  const u16* Bbase = Bmat + (size_t)j0*1024;

  auto stage = [&](int kt, int d){
    int k0 = kt*BKK;
    #pragma unroll
    for (int i=0;i<4;i++){
      int q = w*4 + i;
      int row = q*8 + lr8;
      gll16(Abase + (size_t)row*1024 + k0 + lc8*8, (u16*)&As[d][0] + q*512);
      gll16(Bbase + (size_t)row*1024 + k0 + lc8*8, (u16*)&Bs[d][0] + q*512);
    }
  };
  auto compute = [&](int d){
    #pragma unroll
    for (int kk=0; kk<2; ++kk){
      bf16x8 af[4], bfr[4];
      #pragma unroll
      for (int mi=0;mi<4;mi++)
        af[mi] = *reinterpret_cast<const bf16x8*>(&As[d][(wr*64+mi*16+lrow)*BKK + kk*32 + kgrp*8]);
      #pragma unroll
      for (int ji=0;ji<4;ji++)
        bfr[ji] = *reinterpret_cast<const bf16x8*>(&Bs[d][(wc*64+ji*16+lrow)*BKK + kk*32 + kgrp*8]);
      #pragma unroll
      for (int mi=0;mi<4;mi++)
        #pragma unroll
        for (int ji=0;ji<4;ji++)
          acc[mi][ji] = __builtin_amdgcn_mfma_f32_16x16x32_bf16(af[mi], bfr[ji], acc[mi][ji], 0, 0, 0);
    }
  };

  stage(0, 0);
  #pragma unroll 1
  for (int kt2=0; kt2<8; ++kt2){
    stage(2*kt2+1, 1);
    asm volatile("s_waitcnt vmcnt(8)" ::: "memory");
    __builtin_amdgcn_s_barrier();
    compute(0);
    __builtin_amdgcn_s_barrier();
    if (kt2 < 7){
      stage(2*kt2+2, 0);
      asm volatile("s_waitcnt vmcnt(8)" ::: "memory");
    } else {
      asm volatile("s_waitcnt vmcnt(0)" ::: "memory");
    }
    __builtin_amdgcn_s_barrier();
    compute(1);
    __builtin_amdgcn_s_barrier();
  }

  #pragma unroll
  for (int mi=0;mi<4;mi++){
    #pragma unroll
    for (int ji=0;ji<4;ji++){
      int jg = j0 + wc*64 + ji*16 + lrow;
      int mg = m0 + wr*64 + mi*16 + kgrp*4;
      ushort4 st;
      st.x = f2bf(acc[mi][ji][0]);
      st.y = f2bf(acc[mi][ji][1]);
      st.z = f2bf(acc[mi][ji][2]);
      st.w = f2bf(acc[mi][ji][3]);
      *reinterpret_cast<ushort4*>(&Out[(size_t)jg*NN + mg]) = st;
    }
  }
}

// ---------- fused 6-term GEMM (R11-proven main loop) + fused f32 transpose epilogue ----------
__global__ __launch_bounds__(512) void k_gemm6p(
    const u16* __restrict__ At, const u16* __restrict__ At2,
    const u16* __restrict__ U, const u16* __restrict__ Base,
    float* __restrict__ y){
  __shared__ __align__(16) u16 lds[2][28672];   // per buf: A 256x64 @0, B 192x64 @16384
  const int tid = threadIdx.x;
  const int w = tid >> 6, lane = tid & 63;
  const int lrow = lane & 15, kgrp = lane >> 4;
  const int wm = w & 3, wj = w >> 2;
  const int swz = (lrow & 7) << 3;           // read-side XOR (u16 units, 16B slots)

  const int orig = blockIdx.x;
  const int wg = (orig & 7)*32 + (orig >> 3);  // bijective XCD remap (256 = 8*32)
  const int m0 = (wg >> 6) * 256;
  const int j0 = (wg & 63) * 192;

  const int srow = lane >> 3;
  const int skoff = ((lane & 7) << 3) ^ ((srow & 7) << 3);   // inverse-swizzled k-off
  size_t rowoff[7]; int ldsoff[7]; bool isA[7];
  #pragma unroll
  for (int i=0;i<7;i++){
    int c = w*7 + i;
    if (c < 32){
      int row = c*8 + srow;
      isA[i] = true;  rowoff[i] = (size_t)(m0 + row)*1024 + skoff;  ldsoff[i] = c*512;
    } else {
      int cb = c - 32;
      int row = cb*8 + srow;
      isA[i] = false; rowoff[i] = (size_t)(j0 + row)*1024 + skoff;  ldsoff[i] = 16384 + cb*512;
    }
  }

  #define STAGE(t, i) {                                                        \
    int s_ = (t) >> 4;                                                         \
    int k0_ = ((t) & 15) << 6;                                                 \
    const u16* Ab_ = ((s_ & 1) ? At2 : At) + (size_t)(s_ >> 1)*NN*NN;          \
    const u16* src_ = (isA[i] ? Ab_ : (U + (size_t)s_*HBE)) + rowoff[i] + k0_; \
    gll16(src_, &lds[(t) & 1][ldsoff[i]]); }

  f32x4 acc[4][6];
  #pragma unroll
  for (int mi=0;mi<4;mi++)
    #pragma unroll
    for (int ji=0;ji<6;ji++)
      acc[mi][ji] = (f32x4){0.f,0.f,0.f,0.f};

  #pragma unroll
  for (int i=0;i<7;i++) STAGE(0, i)

  #pragma unroll 1
  for (int t=0; t<96; ++t){
    const int d = t & 1;
    if (t < 95){
      STAGE(t+1, 0) STAGE(t+1, 1)
      asm volatile("s_waitcnt vmcnt(2)" ::: "memory");
    } else {
      asm volatile("s_waitcnt vmcnt(0)" ::: "memory");
    }
    __builtin_amdgcn_s_barrier();
    __builtin_amdgcn_sched_barrier(0);

    bf16x8 bf[6][2];
    #pragma unroll
    for (int p=0;p<4;p++){
      if (t < 95){
        if (p==0){ STAGE(t+1, 2) STAGE(t+1, 3) }
        else if (p==1){ STAGE(t+1, 4) STAGE(t+1, 5) }
        else if (p==2){ STAGE(t+1, 6) }
      }
      if (p==0){
        #pragma unroll
        for (int ji=0;ji<6;ji++){
          int row = wj*96 + ji*16 + lrow;
          #pragma unroll
          for (int kk=0;kk<2;kk++)
            bf[ji][kk] = *reinterpret_cast<const bf16x8*>(
              &lds[d][16384 + row*64 + ((kk*32 + kgrp*8) ^ swz)]);
        }
      }
      bf16x8 af0, af1;
      {
        int row = wm*64 + p*16 + lrow;
        af0 = *reinterpret_cast<const bf16x8*>(&lds[d][row*64 + ((kgrp*8) ^ swz)]);
        af1 = *reinterpret_cast<const bf16x8*>(&lds[d][row*64 + ((32 + kgrp*8) ^ swz)]);
      }
      __builtin_amdgcn_s_setprio(1);
      #pragma unroll
      for (int ji=0;ji<6;ji++){
        acc[p][ji] = __builtin_amdgcn_mfma_f32_16x16x32_bf16(af0, bf[ji][0], acc[p][ji], 0, 0, 0);
        acc[p][ji] = __builtin_amdgcn_mfma_f32_16x16x32_bf16(af1, bf[ji][1], acc[p][ji], 0, 0, 0);
      }
      __builtin_amdgcn_s_setprio(0);
    }
    __builtin_amdgcn_s_barrier();   // all waves done reading buf d before t+2 stages hit it
  }
  #undef STAGE

  // ---- fused transpose epilogue: y[bo][n][t] f32, via LDS, fully coalesced ----
  float* ldsf = (float*)&lds[0][0];           // 96 KB of the 112 KB staging LDS
  const int bo0 = j0 / NT;                    // j0 % 12 == 0
  #pragma unroll 1
  for (int r=0; r<2; ++r){
    if (r) __syncthreads();                   // round-0 readers done before round-1 writers
    if (wj == r){
      #pragma unroll
      for (int ji=0;ji<6;ji++){
        int jl = ji*16 + lrow;                // 0..95 within this wj half
        int bo8 = jl / NT, tt = jl - bo8*NT;  // bo8 in 0..7
        int jg = j0 + r*96 + jl;
        #pragma unroll
        for (int mi=0;mi<4;mi++){
          int nl = wm*64 + mi*16 + kgrp*4;
          const ushort4 bv = *reinterpret_cast<const ushort4*>(&Base[(size_t)jg*NN + m0 + nl]);
          float* p = ldsf + bo8*3072 + nl*NT + tt;
          p[0]  = acc[mi][ji][0] + bf2f(bv.x);
          p[12] = acc[mi][ji][1] + bf2f(bv.y);
          p[24] = acc[mi][ji][2] + bf2f(bv.z);
          p[36] = acc[mi][ji][3] + bf2f(bv.w);
        }
      }
    }
    __syncthreads();                          // writers done before readers
    #pragma unroll
    for (int q=0;q<12;q++){
      int idx = tid + q*512;                  // 6144 float4 per round
      int bo8 = idx / 768, off = (idx - bo8*768)*4;
      *reinterpret_cast<float4*>(y + ((size_t)(bo0 + r*8 + bo8))*(NN*NT) + (size_t)m0*NT + off)
        = *reinterpret_cast<const float4*>(ldsf + bo8*3072 + off);
    }
  }
}

// ---------- final channel mix (fallback path only) ----------
__global__ __launch_bounds__(256) void k_mix7(u16* zt_y,
    const u16* __restrict__ Db, const float* __restrict__ W,
    const float* __restrict__ bias){
  __shared__ u32 X[112][64];   // 28 KB
  int tid = threadIdx.x;
  int n0 = blockIdx.x*128;
  int bt = blockIdx.y;
  int b = bt / NT, t = bt - b*NT;
  int lane = tid & 63;
  int og = __builtin_amdgcn_readfirstlane(tid >> 6);

  float a0[8], a1[8];
  #pragma unroll
  for (int oo=0;oo<8;oo++){ float bv = bias[og*8+oo]; a0[oo]=bv; a1[oo]=bv; }

  #pragma unroll 1
  for (int chunk=0; chunk<2; ++chunk){
    if (chunk) __syncthreads();
    #pragma unroll
    for (int k=0;k<28;k++){
      int i = tid + k*256;
      int rl = i >> 6, col = i & 63;
      int r = chunk*112 + rl;
      int s = r >> 5, c = r & 31;
      const u16* src = (s==0) ? zt_y : (Db + (size_t)(s-1)*HBE);
      X[rl][col] = *reinterpret_cast<const u32*>(src + ((size_t)(b*NC + c)*NT + t)*NN + n0 + 2*col);
    }
    __syncthreads();
    #pragma unroll
    for (int cc=0; cc<112; ++cc){
      u32 xp = X[cc][lane];
      float xl = bflo(xp), xh = bfhi(xp);
      #pragma unroll
      for (int oo=0;oo<8;oo++){
        float w = W[(size_t)(og*8+oo)*TIN + chunk*112 + cc];
        a0[oo] += w*xl; a1[oo] += w*xh;
      }
    }
  }

  #pragma unroll
  for (int oo=0;oo<8;oo++){
    u32 pk = (u32)f2bf(a0[oo]) | ((u32)f2bf(a1[oo]) << 16);
    *reinterpret_cast<u32*>(zt_y + ((size_t)(b*NO + og*8+oo)*NT + t)*NN + n0 + 2*lane) = pk;
  }
}

// ---------- final transpose (fallback path) ----------
__global__ __launch_bounds__(256) void k_out2(const u16* __restrict__ Yb,
                                              float* __restrict__ y){
  __shared__ float tl[256][13];
  int n0 = blockIdx.x*256;
  int bo = blockIdx.y;
  int tid = threadIdx.x;
  #pragma unroll
  for (int k=0;k<12;k++)
    tl[tid][k] = bf2f(Yb[((size_t)bo*NT + k)*NN + n0 + tid]);
  __syncthreads();
  float* yp = y + ((size_t)bo*NN + n0)*NT;
  #pragma unroll
  for (int k=0;k<12;k++){
    int i = k*256 + tid;
    yp[i] = tl[i/12][i%12];
  }
}

extern "C" void kernel_launch(void* const* d_in, const int* in_sizes, int n_in,
                              void* d_out, int out_size, void* d_ws, size_t ws_size,
                              hipStream_t stream){
  const float* x    = (const float*)d_in[0];
  const float* a0   = (const float*)d_in[1];
  const float* a1   = (const float*)d_in[2];
  const float* a2   = (const float*)d_in[3];
  const float* W    = (const float*)d_in[4];
  const float* bias = (const float*)d_in[5];
  float* y = (float*)d_out;
  (void)in_sizes; (void)n_in; (void)out_size;

  const size_t atB = (size_t)3*NN*NN*2;     // 6.29 MB
  const size_t ztB = HBE*2;                 // 25.17 MB
  const size_t need_fused = 2*atB + 8*ztB;  // 213.9 MB (R9-R15 verified available)

  if (ws_size >= need_fused){
    char* ws = (char*)d_ws;
    u16* At   = (u16*)ws;  ws += atB;
    u16* At2  = (u16*)ws;  ws += atB;
    ws += ztB;                               // (former Zc slot, unused in primary)
    u16* U    = (u16*)ws;  ws += 6*ztB;
    u16* Base = (u16*)ws;  ws += ztB;
    u16* Ar   = Base;                        // dead after k_bgemm<0>, before pmix2 writes Base

    k_prep_adj<<<dim3(32,32,3), dim3(32,8), 0, stream>>>(a0, a1, a2, At, Ar);
    k_bgemm<0><<<dim3(NN/128, NN/128, 3), 256, 0, stream>>>(At, Ar, At2, nullptr, U);
    k_pmix2<<<dim3(NN/64, NB), 256, 0, stream>>>(x, W, bias, U, Base);
    k_gemm6p<<<256, 512, 0, stream>>>(At, At2, U, Base, y);         // writes y directly
  } else {
    // fallback: two dependent batched GEMM dispatches + late mix
    char* ws = (char*)d_ws;
    u16* At  = (u16*)ws;  ws += atB;
    u16* Zt  = (u16*)ws;  ws += ztB;
    u16* Db  = (u16*)ws;  ws += 6*ztB;
    u16* Ar  = Db + 6*HBE - (size_t)3*NN*NN;

    k_prep_adj<<<dim3(32,32,3), dim3(32,8), 0, stream>>>(a0, a1, a2, At, Ar);
    k_prep_x2 <<<dim3(NN/64, NB*NC), 256, 0, stream>>>(x, Zt);
    k_bgemm<2><<<dim3(NJ/128, NN/128, 3), 256, 0, stream>>>(At, Ar, At, Zt, Db);
    k_bgemm<3><<<dim3(NJ/128, NN/128, 3), 256, 0, stream>>>(At, Ar, At, Zt, Db);
    k_mix7<<<dim3(NN/128, NB*NT), 256, 0, stream>>>(Zt, Db, W, bias);
    k_out2<<<dim3(NN/256, NB*NO), 256, 0, stream>>>(Zt, y);
  }
}